// Round 6
// baseline (487.977 us; speedup 1.0000x reference)
//
#include <hip/hip_runtime.h>
#include <math.h>

#define N_USERS 100000
#define N_ITEMS 50000
#define N_NODES 150000
#define EMB 64
#define NI 128
#define NUM_EDGES 4000000
#define NPAD 150016            // 586 * 256
#define NB 586                 // buckets of 256 nodes
#define BSTRIDE 8192           // fixed slots per bucket (mean 6827+pad 7211, sigma ~85)
#define ETILE 8192
#define EGRID ((NUM_EDGES + ETILE - 1) / ETILE)   // 489
#define NT_ALL (NPAD / 16)     // 9376 tiles (covers dummy pad nodes; writes guarded)
#define SBLK (NT_ALL / 4)      // 2344 blocks x 4 waves
#define SENT 150000u           // sentinel node: dinv==0, ebf row zeroed

typedef __attribute__((ext_vector_type(8))) short bf16x8;
typedef __attribute__((ext_vector_type(4))) float f32x4;

__device__ __forceinline__ unsigned short f2bf(float f) {
    unsigned int u = __float_as_uint(f);
    u += 0x7FFFu + ((u >> 16) & 1u);
    return (unsigned short)(u >> 16);
}
__device__ __forceinline__ float bflo(unsigned int u) { return __uint_as_float(u << 16); }
__device__ __forceinline__ float bfhi(unsigned int u) { return __uint_as_float(u & 0xFFFF0000u); }

// ---- bucket scatter: block-aggregated reservations into fixed-stride buckets ----

__global__ __launch_bounds__(512) void bucket_scatter(const int* __restrict__ h,
                                                      const int* __restrict__ t,
                                                      int* __restrict__ gcur,
                                                      unsigned int* __restrict__ ebuf) {
    __shared__ int lc[NB];
    __shared__ int lbase[NB];
    __shared__ int lcur[NB];
    int tid = threadIdx.x;
    for (int i = tid; i < NB; i += 512) lc[i] = 0;
    __syncthreads();
    int base = blockIdx.x * ETILE;
#pragma unroll
    for (int k = 0; k < ETILE / 512; ++k) {
        int idx = base + k * 512 + tid;
        if (idx < NUM_EDGES) atomicAdd(&lc[h[idx] >> 8], 1);
    }
    __syncthreads();
    for (int i = tid; i < NB; i += 512) {
        int c = lc[i];
        lbase[i] = c ? (i * BSTRIDE + atomicAdd(&gcur[i], c)) : 0;
        lcur[i] = 0;
    }
    __syncthreads();
#pragma unroll
    for (int k = 0; k < ETILE / 512; ++k) {
        int idx = base + k * 512 + tid;
        if (idx < NUM_EDGES) {
            int hh = h[idx], tt = t[idx];
            int b = hh >> 8;
            int p = lbase[b] + atomicAdd(&lcur[b], 1);
            int lim = b * BSTRIDE + BSTRIDE - 1;
            p = (p <= lim) ? p : lim;
            ebuf[p] = ((unsigned int)(hh & 255) << 18) | (unsigned int)tt;
        }
    }
}

// ---- per-bucket counting sort + degree-sort perm + pad-to-4 segments ----
// rmeta[node] = (padded start, padded count). Pad slots filled with SENT
// (dinv==0, ebf row zeroed) so the gather needs no predication/clamps.
// perm: within each bucket, nodes ordered by descending degree -> tiles of
// 16 consecutive perm entries have near-equal degree (gather lane balance).

__global__ __launch_bounds__(512) void bucket_csr(const int* __restrict__ gcur,
                                                  unsigned int* __restrict__ ebuf,
                                                  int2* __restrict__ rmeta,
                                                  float* __restrict__ dinv,
                                                  int* __restrict__ perm) {
    __shared__ unsigned int in_s[BSTRIDE];   // 32 KB
    __shared__ int cnt_s[256];
    __shared__ int base_s[256];
    __shared__ int sc[256];
    __shared__ int dh[256];
    __shared__ int dcur[256];
    int b = blockIdx.x, tid = threadIdx.x;
    int s = b * BSTRIDE;
    int n = gcur[b];
    if (n > BSTRIDE) n = BSTRIDE;

    for (int i = tid; i < n; i += 512) in_s[i] = ebuf[s + i];
    if (tid < 256) { cnt_s[tid] = 0; dh[tid] = 0; dcur[tid] = 0; }
    __syncthreads();
    for (int i = tid; i < n; i += 512) atomicAdd(&cnt_s[in_s[i] >> 18], 1);
    __syncthreads();

    int c = 0, pc = 0, key = 0;
    if (tid < 256) {
        c = cnt_s[tid];
        pc = (c + 3) & ~3;              // pad each row segment to %4
        sc[tid] = pc;
        key = 255 - min(c, 255);        // descending-degree bin
        atomicAdd(&dh[key], 1);
    }
    __syncthreads();
    // scan 1: padded counts -> segment starts
    for (int off = 1; off < 256; off <<= 1) {
        int tv = 0;
        if (tid < 256 && tid >= off) tv = sc[tid - off];
        __syncthreads();
        if (tid < 256 && tid >= off) sc[tid] += tv;
        __syncthreads();
    }
    int excl = 0;
    if (tid < 256) { excl = sc[tid] - pc; base_s[tid] = excl; }
    __syncthreads();
    // scan 2: degree-bin histogram -> sort bases
    if (tid < 256) sc[tid] = dh[tid];
    __syncthreads();
    for (int off = 1; off < 256; off <<= 1) {
        int tv = 0;
        if (tid < 256 && tid >= off) tv = sc[tid - off];
        __syncthreads();
        if (tid < 256 && tid >= off) sc[tid] += tv;
        __syncthreads();
    }
    if (tid < 256) {
        int node = (b << 8) + tid;
        rmeta[node] = make_int2(s + excl, pc);
        dinv[node] = (c > 0) ? rsqrtf((float)c) : 0.0f;
        int pos = (sc[key] - dh[key]) + atomicAdd(&dcur[key], 1);
        perm[(b << 8) + pos] = node;
        // fill pad slots with sentinel (padded total <= BSTRIDE: 12-sigma margin)
        for (int p2 = c; p2 < pc; ++p2) ebuf[s + excl + p2] = SENT;
        cnt_s[tid] = 0;
    }
    __syncthreads();
    for (int i = tid; i < n; i += 512) {
        unsigned int qv = in_s[i];
        int hl = (int)(qv >> 18);
        int p = base_s[hl] + atomicAdd(&cnt_s[hl], 1);
        ebuf[s + p] = qv & 0x3FFFFu;    // pure t index, sorted+padded position
    }
}

// ---- init: ebf = bf16(concat(user,item)) + zeroed dummy rows; acc = concat ----

__global__ void init_kernel(const float4* __restrict__ ue4, const float4* __restrict__ ie4,
                            uint2* __restrict__ ebf4, float4* __restrict__ out4) {
    int i = blockIdx.x * blockDim.x + threadIdx.x;
    const int uelems = N_USERS * EMB / 4;
    const int relems = N_NODES * EMB / 4;
    const int total  = NPAD * EMB / 4;
    if (i < total) {
        float4 v = make_float4(0.f, 0.f, 0.f, 0.f);
        if (i < uelems) v = ue4[i];
        else if (i < relems) v = ie4[i - uelems];
        if (i < relems) out4[i] = v;
        unsigned int p0 = ((unsigned int)f2bf(v.y) << 16) | f2bf(v.x);
        unsigned int p1 = ((unsigned int)f2bf(v.w) << 16) | f2bf(v.z);
        ebf4[i] = make_uint2(p0, p1);
    }
}

// ---- wconv: W fp32 -> two bf16 global tables (16 KB each, L1/L2-resident) ----

__global__ __launch_bounds__(256) void wconv(const float* __restrict__ W,
                                             unsigned short* __restrict__ Wt,
                                             unsigned short* __restrict__ W2b) {
    int i = blockIdx.x * 256 + threadIdx.x;
    if (i < EMB * NI) {
        int d = i >> 7, c = i & 127;
        unsigned short b = f2bf(W[i]);
        W2b[i] = b;                 // [dim][intent]
        Wt[c * EMB + d] = b;        // [intent][dim]
    }
}

// ---- fused SpMM + MFMA intent head (barrier-free, degree-balanced) ----
// One 16-row tile per wave (rows = perm[tile*16 .. +15], near-equal degree).
// Block = 256 (4 waves). LDS 22528 B -> 7 blocks/CU.
// Gather: lane = (qq row 0..7, cc dim-oct 0..7); per-lane loop to its own
//   padded count (exec-mask divergence ~0 after degree sort); one AND per
//   index, no clamps, no predication (pads hit SENT: dinv==0, zero row).
//   2-deep pipeline: col 2 groups ahead, dinv+uint4 1 group ahead.

__global__ __launch_bounds__(256, 7) void spmm_intent(const int2* __restrict__ rmeta,
                                                      const unsigned int* __restrict__ col,
                                                      const float* __restrict__ dinv,
                                                      const int* __restrict__ perm,
                                                      const unsigned short* __restrict__ ebf,
                                                      unsigned short* __restrict__ ebfout,
                                                      const unsigned short* __restrict__ Wt,
                                                      const unsigned short* __restrict__ W2b,
                                                      float* __restrict__ acc, float scale) {
    __shared__ __align__(16) float UPool[4][1408];   // 22528 B

    int tid = threadIdx.x;
    int wid = tid >> 6, lane = tid & 63;
    int q = lane >> 4, c = lane & 15;        // matmul decomposition
    int qq = lane >> 3, cc = lane & 7;       // gather decomposition
    int tile = blockIdx.x * 4 + wid;
    if (tile >= NT_ALL) return;
    int rowbase = tile << 4;
    float* fw = &UPool[wid][0];
    unsigned short* pw = (unsigned short*)&UPool[wid][1088];

    // ---- phase 1: gather, two 8-row halves ----
#pragma unroll 1
    for (int half = 0; half < 2; ++half) {
        int prow = perm[rowbase + half * 8 + qq];
        int2 rm = rmeta[prow];
        int s = rm.x, pcv = rm.y;            // padded count (multiple of 4)
        float dr = dinv[prow];

        float a0 = 0.f, a1 = 0.f, a2 = 0.f, a3 = 0.f;
        float a4 = 0.f, a5 = 0.f, a6 = 0.f, a7 = 0.f;
        const unsigned short* eb = ebf + (cc << 3);

        // prologue: group0 fully issued; group1 addresses staged
        int e0 = (int)(col[s]     & 0x3FFFFu);
        int e1 = (int)(col[s + 1] & 0x3FFFFu);
        int e2 = (int)(col[s + 2] & 0x3FFFFu);
        int e3 = (int)(col[s + 3] & 0x3FFFFu);
        float g0 = dinv[e0], g1 = dinv[e1], g2 = dinv[e2], g3 = dinv[e3];
        uint4 u0 = *(const uint4*)(eb + ((size_t)e0 << 6));
        uint4 u1 = *(const uint4*)(eb + ((size_t)e1 << 6));
        uint4 u2 = *(const uint4*)(eb + ((size_t)e2 << 6));
        uint4 u3 = *(const uint4*)(eb + ((size_t)e3 << 6));
        int f0 = (int)(col[s + 4] & 0x3FFFFu);
        int f1 = (int)(col[s + 5] & 0x3FFFFu);
        int f2 = (int)(col[s + 6] & 0x3FFFFu);
        int f3 = (int)(col[s + 7] & 0x3FFFFu);

        for (int it = 0; it < pcv; it += 4) {
            // issue group it+4 loads
            float h0 = dinv[f0], h1 = dinv[f1], h2 = dinv[f2], h3 = dinv[f3];
            uint4 v0 = *(const uint4*)(eb + ((size_t)f0 << 6));
            uint4 v1 = *(const uint4*)(eb + ((size_t)f1 << 6));
            uint4 v2 = *(const uint4*)(eb + ((size_t)f2 << 6));
            uint4 v3 = *(const uint4*)(eb + ((size_t)f3 << 6));
            // issue col for group it+8
            int x0 = (int)(col[s + it + 8]  & 0x3FFFFu);
            int x1 = (int)(col[s + it + 9]  & 0x3FFFFu);
            int x2 = (int)(col[s + it + 10] & 0x3FFFFu);
            int x3 = (int)(col[s + it + 11] & 0x3FFFFu);
            // consume group it (no predication: pads have g==0, zero rows)
            a0 = fmaf(g0, bflo(u0.x), a0); a1 = fmaf(g0, bfhi(u0.x), a1);
            a2 = fmaf(g0, bflo(u0.y), a2); a3 = fmaf(g0, bfhi(u0.y), a3);
            a4 = fmaf(g0, bflo(u0.z), a4); a5 = fmaf(g0, bfhi(u0.z), a5);
            a6 = fmaf(g0, bflo(u0.w), a6); a7 = fmaf(g0, bfhi(u0.w), a7);
            a0 = fmaf(g1, bflo(u1.x), a0); a1 = fmaf(g1, bfhi(u1.x), a1);
            a2 = fmaf(g1, bflo(u1.y), a2); a3 = fmaf(g1, bfhi(u1.y), a3);
            a4 = fmaf(g1, bflo(u1.z), a4); a5 = fmaf(g1, bfhi(u1.z), a5);
            a6 = fmaf(g1, bflo(u1.w), a6); a7 = fmaf(g1, bfhi(u1.w), a7);
            a0 = fmaf(g2, bflo(u2.x), a0); a1 = fmaf(g2, bfhi(u2.x), a1);
            a2 = fmaf(g2, bflo(u2.y), a2); a3 = fmaf(g2, bfhi(u2.y), a3);
            a4 = fmaf(g2, bflo(u2.z), a4); a5 = fmaf(g2, bfhi(u2.z), a5);
            a6 = fmaf(g2, bflo(u2.w), a6); a7 = fmaf(g2, bfhi(u2.w), a7);
            a0 = fmaf(g3, bflo(u3.x), a0); a1 = fmaf(g3, bfhi(u3.x), a1);
            a2 = fmaf(g3, bflo(u3.y), a2); a3 = fmaf(g3, bfhi(u3.y), a3);
            a4 = fmaf(g3, bflo(u3.z), a4); a5 = fmaf(g3, bfhi(u3.z), a5);
            a6 = fmaf(g3, bflo(u3.w), a6); a7 = fmaf(g3, bfhi(u3.w), a7);
            // rotate pipeline
            u0 = v0; u1 = v1; u2 = v2; u3 = v3;
            g0 = h0; g1 = h1; g2 = h2; g3 = h3;
            f0 = x0; f1 = x1; f2 = x2; f3 = x3;
        }
        int fb = (half * 8 + qq) * 68 + (cc << 3);
        fw[fb + 0] = a0 * dr; fw[fb + 1] = a1 * dr;
        fw[fb + 2] = a2 * dr; fw[fb + 3] = a3 * dr;
        fw[fb + 4] = a4 * dr; fw[fb + 5] = a5 * dr;
        fw[fb + 6] = a6 * dr; fw[fb + 7] = a7 * dr;
    }

    // ---- phase 2: matmul1 S = E @ W ----
    int arow = perm[rowbase + c];
    const unsigned short* erow = ebf + ((size_t)arow << 6);
    bf16x8 A0 = *(const bf16x8*)(erow + (q << 3));
    bf16x8 A1 = *(const bf16x8*)(erow + 32 + (q << 3));
    f32x4 S[8];
#pragma unroll
    for (int t = 0; t < 8; ++t) {
        bf16x8 B0 = *(const bf16x8*)&Wt[(16 * t + c) * EMB + (q << 3)];
        bf16x8 B1 = *(const bf16x8*)&Wt[(16 * t + c) * EMB + 32 + (q << 3)];
        f32x4 z = {0.f, 0.f, 0.f, 0.f};
        z = __builtin_amdgcn_mfma_f32_16x16x32_bf16(A0, B0, z, 0, 0, 0);
        S[t] = __builtin_amdgcn_mfma_f32_16x16x32_bf16(A1, B1, z, 0, 0, 0);
    }

    // ---- phase 3: softmax over 128 intents, per C-row (row = 4q + r) ----
#pragma unroll
    for (int r = 0; r < 4; ++r) {
        float m = S[0][r];
#pragma unroll
        for (int t = 1; t < 8; ++t) m = fmaxf(m, S[t][r]);
        m = fmaxf(m, __shfl_xor(m, 1)); m = fmaxf(m, __shfl_xor(m, 2));
        m = fmaxf(m, __shfl_xor(m, 4)); m = fmaxf(m, __shfl_xor(m, 8));
        float sum = 0.f;
#pragma unroll
        for (int t = 0; t < 8; ++t) { float ex = __expf(S[t][r] - m); S[t][r] = ex; sum += ex; }
        sum += __shfl_xor(sum, 1); sum += __shfl_xor(sum, 2);
        sum += __shfl_xor(sum, 4); sum += __shfl_xor(sum, 8);
        float inv = 1.0f / sum;
#pragma unroll
        for (int t = 0; t < 8; ++t) S[t][r] *= inv;
    }

    // ---- phase 4: matmul2 O = P @ W^T, hi/lo bf16 split ----
    f32x4 O0 = {0.f, 0.f, 0.f, 0.f}, O1 = O0, O2 = O0, O3 = O0;
#pragma unroll
    for (int s2 = 0; s2 < 4; ++s2) {
#pragma unroll
        for (int h2 = 0; h2 < 2; ++h2) {
            int t = 2 * s2 + h2;
#pragma unroll
            for (int r = 0; r < 4; ++r) {
                float p = S[t][r];
                unsigned short b = f2bf(p);
                pw[(4 * q + r) * 40 + (h2 << 4) + c] = b;
                S[t][r] = p - bflo((unsigned int)b);
            }
        }
        bf16x8 Pf = *(const bf16x8*)&pw[c * 40 + (q << 3)];
        {
            bf16x8 Bf0 = *(const bf16x8*)&W2b[(c) * NI + (s2 << 5) + (q << 3)];
            bf16x8 Bf1 = *(const bf16x8*)&W2b[(16 + c) * NI + (s2 << 5) + (q << 3)];
            O0 = __builtin_amdgcn_mfma_f32_16x16x32_bf16(Pf, Bf0, O0, 0, 0, 0);
            O1 = __builtin_amdgcn_mfma_f32_16x16x32_bf16(Pf, Bf1, O1, 0, 0, 0);
            bf16x8 Bf2 = *(const bf16x8*)&W2b[(32 + c) * NI + (s2 << 5) + (q << 3)];
            bf16x8 Bf3 = *(const bf16x8*)&W2b[(48 + c) * NI + (s2 << 5) + (q << 3)];
            O2 = __builtin_amdgcn_mfma_f32_16x16x32_bf16(Pf, Bf2, O2, 0, 0, 0);
            O3 = __builtin_amdgcn_mfma_f32_16x16x32_bf16(Pf, Bf3, O3, 0, 0, 0);
        }
#pragma unroll
        for (int h2 = 0; h2 < 2; ++h2) {
            int t = 2 * s2 + h2;
#pragma unroll
            for (int r = 0; r < 4; ++r)
                pw[(4 * q + r) * 40 + (h2 << 4) + c] = f2bf(S[t][r]);
        }
        bf16x8 Pl = *(const bf16x8*)&pw[c * 40 + (q << 3)];
        {
            bf16x8 Bf0 = *(const bf16x8*)&W2b[(c) * NI + (s2 << 5) + (q << 3)];
            bf16x8 Bf1 = *(const bf16x8*)&W2b[(16 + c) * NI + (s2 << 5) + (q << 3)];
            O0 = __builtin_amdgcn_mfma_f32_16x16x32_bf16(Pl, Bf0, O0, 0, 0, 0);
            O1 = __builtin_amdgcn_mfma_f32_16x16x32_bf16(Pl, Bf1, O1, 0, 0, 0);
            bf16x8 Bf2 = *(const bf16x8*)&W2b[(32 + c) * NI + (s2 << 5) + (q << 3)];
            bf16x8 Bf3 = *(const bf16x8*)&W2b[(48 + c) * NI + (s2 << 5) + (q << 3)];
            O2 = __builtin_amdgcn_mfma_f32_16x16x32_bf16(Pl, Bf2, O2, 0, 0, 0);
            O3 = __builtin_amdgcn_mfma_f32_16x16x32_bf16(Pl, Bf3, O3, 0, 0, 0);
        }
    }

    asm volatile("" ::: "memory");

    // ---- phase 5a: fold O into fw (nv = gnn + O), wave-local ----
#pragma unroll
    for (int r = 0; r < 4; ++r) {
        int rl = 4 * q + r;
        float* gr = &fw[rl * 68];
        gr[c]      += O0[r];
        gr[16 + c] += O1[r];
        gr[32 + c] += O2[r];
        gr[48 + c] += O3[r];
    }

    // ---- phase 5b: coalesced write-out; lane = (row j, 16-float segment sg) ----
    {
        int j = lane >> 2, sg = lane & 3;
        int rw = perm[rowbase + j];
        const float* gr = &fw[j * 68 + (sg << 4)];
        float4 x0 = *(const float4*)&gr[0];
        float4 x1 = *(const float4*)&gr[4];
        float4 x2 = *(const float4*)&gr[8];
        float4 x3 = *(const float4*)&gr[12];
        size_t base = ((size_t)rw << 6) + (sg << 4);   // element index
        uint4 w0, w1;
        w0.x = (unsigned int)f2bf(x0.x) | ((unsigned int)f2bf(x0.y) << 16);
        w0.y = (unsigned int)f2bf(x0.z) | ((unsigned int)f2bf(x0.w) << 16);
        w0.z = (unsigned int)f2bf(x1.x) | ((unsigned int)f2bf(x1.y) << 16);
        w0.w = (unsigned int)f2bf(x1.z) | ((unsigned int)f2bf(x1.w) << 16);
        w1.x = (unsigned int)f2bf(x2.x) | ((unsigned int)f2bf(x2.y) << 16);
        w1.y = (unsigned int)f2bf(x2.z) | ((unsigned int)f2bf(x2.w) << 16);
        w1.z = (unsigned int)f2bf(x3.x) | ((unsigned int)f2bf(x3.y) << 16);
        w1.w = (unsigned int)f2bf(x3.z) | ((unsigned int)f2bf(x3.w) << 16);
        *(uint4*)(ebfout + base) = w0;
        *(uint4*)(ebfout + base + 8) = w1;
        if (rw < N_NODES) {
            float4* ap = (float4*)(acc + base);
            float4 b0 = ap[0], b1 = ap[1], b2 = ap[2], b3 = ap[3];
            b0.x = (b0.x + x0.x) * scale; b0.y = (b0.y + x0.y) * scale;
            b0.z = (b0.z + x0.z) * scale; b0.w = (b0.w + x0.w) * scale;
            b1.x = (b1.x + x1.x) * scale; b1.y = (b1.y + x1.y) * scale;
            b1.z = (b1.z + x1.z) * scale; b1.w = (b1.w + x1.w) * scale;
            b2.x = (b2.x + x2.x) * scale; b2.y = (b2.y + x2.y) * scale;
            b2.z = (b2.z + x2.z) * scale; b2.w = (b2.w + x2.w) * scale;
            b3.x = (b3.x + x3.x) * scale; b3.y = (b3.y + x3.y) * scale;
            b3.z = (b3.z + x3.z) * scale; b3.w = (b3.w + x3.w) * scale;
            ap[0] = b0; ap[1] = b1; ap[2] = b2; ap[3] = b3;
        }
    }
}

// ---- launch ----

extern "C" void kernel_launch(void* const* d_in, const int* in_sizes, int n_in,
                              void* d_out, int out_size, void* d_ws, size_t ws_size,
                              hipStream_t stream) {
    const float* ue = (const float*)d_in[0];
    const float* ie = (const float*)d_in[1];
    const float* W  = (const float*)d_in[2];
    const int*   h  = (const int*)d_in[3];
    const int*   t  = (const int*)d_in[4];
    float* out = (float*)d_out;

    // workspace (4-byte units), ~58 MB. Layout note: each ebf table is followed
    // by >=34 MB of workspace so masked stale prefetch indices (< 2^18) can
    // never read past the allocation.
    int*            gcur  = (int*)d_ws;                           // 1024 (NB used)
    int2*           rmeta = (int2*)(gcur + 1024);                 // NPAD int2
    float*          dinv  = (float*)(rmeta + NPAD);               // NPAD
    int*            perm  = (int*)(dinv + NPAD);                  // NPAD
    unsigned short* ebfA  = (unsigned short*)(perm + NPAD);       // NPAD*64 ushort
    unsigned short* ebfB  = ebfA + (size_t)NPAD * EMB;            // NPAD*64 ushort
    unsigned int*   ebuf  = (unsigned int*)(ebfB + (size_t)NPAD * EMB); // NB*BSTRIDE + 16
    unsigned short* Wt    = (unsigned short*)(ebuf + NB * BSTRIDE + 16);
    unsigned short* W2b   = Wt + EMB * NI;

    hipMemsetAsync(gcur, 0, NB * sizeof(int), stream);
    hipMemsetAsync(ebuf + NB * BSTRIDE, 0, 16 * sizeof(unsigned int), stream);
    bucket_scatter<<<EGRID, 512, 0, stream>>>(h, t, gcur, ebuf);
    bucket_csr<<<NB, 512, 0, stream>>>(gcur, ebuf, rmeta, dinv, perm);
    init_kernel<<<(NPAD * EMB / 4 + 255) / 256, 256, 0, stream>>>(
        (const float4*)ue, (const float4*)ie, (uint2*)ebfA, (float4*)out);
    wconv<<<(EMB * NI + 255) / 256, 256, 0, stream>>>(W, Wt, W2b);

    const unsigned int* col = ebuf;
    spmm_intent<<<SBLK, 256, 0, stream>>>(rmeta, col, dinv, perm, ebfA, ebfB, Wt, W2b, out, 1.0f);
    spmm_intent<<<SBLK, 256, 0, stream>>>(rmeta, col, dinv, perm, ebfB, ebfA, Wt, W2b, out, 1.0f / 3.0f);
}

// Round 8
// 473.200 us; speedup vs baseline: 1.0312x; 1.0312x over previous
//
#include <hip/hip_runtime.h>
#include <math.h>

#define N_USERS 100000
#define N_ITEMS 50000
#define N_NODES 150000
#define EMB 64
#define NI 128
#define NUM_EDGES 4000000
#define NPAD 150016            // 1172 * 128
#define NB 1172                // buckets of 128 nodes
#define BSTRIDE 4352           // slots per bucket (mean 3413+pad<=384, sigma ~58)
#define ETILE 8192
#define EGRID ((NUM_EDGES + ETILE - 1) / ETILE)   // 489
#define NT_ALL (NPAD / 16)     // 9376 tiles (covers dummy pad nodes; writes guarded)
#define SBLK (NT_ALL / 4)      // 2344 blocks x 4 waves
#define SENT 150000u           // sentinel node: dinv==0, ebf row zeroed

typedef __attribute__((ext_vector_type(8))) short bf16x8;
typedef __attribute__((ext_vector_type(4))) float f32x4;

__device__ __forceinline__ unsigned short f2bf(float f) {
    unsigned int u = __float_as_uint(f);
    u += 0x7FFFu + ((u >> 16) & 1u);
    return (unsigned short)(u >> 16);
}
__device__ __forceinline__ float bflo(unsigned int u) { return __uint_as_float(u << 16); }
__device__ __forceinline__ float bfhi(unsigned int u) { return __uint_as_float(u & 0xFFFF0000u); }

// ---- bucket scatter: block-aggregated reservations into fixed-stride buckets ----

__global__ __launch_bounds__(512) void bucket_scatter(const int* __restrict__ h,
                                                      const int* __restrict__ t,
                                                      int* __restrict__ gcur,
                                                      unsigned int* __restrict__ ebuf) {
    __shared__ int lc[NB];
    __shared__ int lbase[NB];
    __shared__ int lcur[NB];
    int tid = threadIdx.x;
    for (int i = tid; i < NB; i += 512) lc[i] = 0;
    __syncthreads();
    int base = blockIdx.x * ETILE;
#pragma unroll
    for (int k = 0; k < ETILE / 512; ++k) {
        int idx = base + k * 512 + tid;
        if (idx < NUM_EDGES) atomicAdd(&lc[h[idx] >> 7], 1);
    }
    __syncthreads();
    for (int i = tid; i < NB; i += 512) {
        int c = lc[i];
        lbase[i] = c ? (i * BSTRIDE + atomicAdd(&gcur[i], c)) : 0;
        lcur[i] = 0;
    }
    __syncthreads();
#pragma unroll
    for (int k = 0; k < ETILE / 512; ++k) {
        int idx = base + k * 512 + tid;
        if (idx < NUM_EDGES) {
            int hh = h[idx], tt = t[idx];
            int b = hh >> 7;
            int p = lbase[b] + atomicAdd(&lcur[b], 1);
            int lim = b * BSTRIDE + BSTRIDE - 1;
            p = (p <= lim) ? p : lim;
            ebuf[p] = ((unsigned int)(hh & 127) << 18) | (unsigned int)tt;
        }
    }
}

// ---- per-bucket counting sort + pad-to-4 segments + WITHIN-TILE degree rank ----
// rmeta[node] = (padded start, padded count). Pad slots filled with SENT
// (dinv==0, ebf row zeroed) so the gather needs no predication/clamps.
// perm: permutation WITHIN each 16-node tile (descending degree) -> gather
// halves get near-equal degrees while all accesses stay in the same 2 KB
// windows as identity ordering (R6 lesson: bucket-wide perm kills locality).

__global__ __launch_bounds__(512) void bucket_csr(const int* __restrict__ gcur,
                                                  unsigned int* __restrict__ ebuf,
                                                  int2* __restrict__ rmeta,
                                                  float* __restrict__ dinv,
                                                  int* __restrict__ perm) {
    __shared__ unsigned int in_s[BSTRIDE];   // 17408 B
    __shared__ int cnt_s[128];
    __shared__ int base_s[128];
    __shared__ int sc[128];
    __shared__ int dg[128];
    int b = blockIdx.x, tid = threadIdx.x;
    int s = b * BSTRIDE;
    int n = gcur[b];
    if (n > BSTRIDE) n = BSTRIDE;

    for (int i = tid; i < n; i += 512) in_s[i] = ebuf[s + i];
    if (tid < 128) cnt_s[tid] = 0;
    __syncthreads();
    for (int i = tid; i < n; i += 512) atomicAdd(&cnt_s[in_s[i] >> 18], 1);
    __syncthreads();

    int c = 0, pc = 0;
    if (tid < 128) {
        c = cnt_s[tid];
        pc = (c + 3) & ~3;              // pad each row segment to %4
        sc[tid] = pc;
        dg[tid] = c;
    }
    __syncthreads();
    // scan: padded counts -> segment starts
    for (int off = 1; off < 128; off <<= 1) {
        int tv = 0;
        if (tid < 128 && tid >= off) tv = sc[tid - off];
        __syncthreads();
        if (tid < 128 && tid >= off) sc[tid] += tv;
        __syncthreads();
    }
    if (tid < 128) {
        int excl = sc[tid] - pc;
        base_s[tid] = excl;
        int node = (b << 7) + tid;
        rmeta[node] = make_int2(s + excl, pc);
        dinv[node] = (c > 0) ? rsqrtf((float)c) : 0.0f;
        // within-tile rank by descending degree (lexicographic tie-break)
        int tb = tid & ~15;
        int rank = 0;
#pragma unroll
        for (int j = 0; j < 16; ++j) {
            int dj = dg[tb + j];
            rank += (dj > c) || (dj == c && (tb + j) < tid);
        }
        perm[(b << 7) + tb + rank] = node;
        // fill pad slots with sentinel
        for (int p2 = c; p2 < pc; ++p2) ebuf[s + excl + p2] = SENT;
        cnt_s[tid] = 0;
    }
    __syncthreads();
    for (int i = tid; i < n; i += 512) {
        unsigned int qv = in_s[i];
        int hl = (int)(qv >> 18);
        int p = base_s[hl] + atomicAdd(&cnt_s[hl], 1);
        ebuf[s + p] = qv & 0x3FFFFu;    // pure t index, sorted+padded position
    }
}

// ---- init: ebf = bf16(concat(user,item)) + zeroed dummy rows; acc = concat ----

__global__ void init_kernel(const float4* __restrict__ ue4, const float4* __restrict__ ie4,
                            uint2* __restrict__ ebf4, float4* __restrict__ out4) {
    int i = blockIdx.x * blockDim.x + threadIdx.x;
    const int uelems = N_USERS * EMB / 4;
    const int relems = N_NODES * EMB / 4;
    const int total  = NPAD * EMB / 4;
    if (i < total) {
        float4 v = make_float4(0.f, 0.f, 0.f, 0.f);
        if (i < uelems) v = ue4[i];
        else if (i < relems) v = ie4[i - uelems];
        if (i < relems) out4[i] = v;
        unsigned int p0 = ((unsigned int)f2bf(v.y) << 16) | f2bf(v.x);
        unsigned int p1 = ((unsigned int)f2bf(v.w) << 16) | f2bf(v.z);
        ebf4[i] = make_uint2(p0, p1);
    }
}

// ---- wconv: W fp32 -> two bf16 global tables (16 KB each, L1/L2-resident) ----

__global__ __launch_bounds__(256) void wconv(const float* __restrict__ W,
                                             unsigned short* __restrict__ Wt,
                                             unsigned short* __restrict__ W2b) {
    int i = blockIdx.x * 256 + threadIdx.x;
    if (i < EMB * NI) {
        int d = i >> 7, c = i & 127;
        unsigned short b = f2bf(W[i]);
        W2b[i] = b;                 // [dim][intent]
        Wt[c * EMB + d] = b;        // [intent][dim]
    }
}

// ---- fused SpMM + MFMA intent head (barrier-free, tile-balanced) ----
// One 16-row tile per wave (rows = perm[tile*16 .. +15]: within-tile degree
// order). Block = 256 (4 waves). LDS 22528 B -> 7 blocks/CU.
// Gather: lane = (qq row 0..7, cc dim-oct 0..7); per-lane loop to its own
//   padded count; one AND per index, no clamps, no predication (pads hit
//   SENT: dinv==0, zero row). 2-deep pipeline: col 2 groups ahead,
//   dinv+uint4 1 group ahead.

__global__ __launch_bounds__(256, 7) void spmm_intent(const int2* __restrict__ rmeta,
                                                      const unsigned int* __restrict__ col,
                                                      const float* __restrict__ dinv,
                                                      const int* __restrict__ perm,
                                                      const unsigned short* __restrict__ ebf,
                                                      unsigned short* __restrict__ ebfout,
                                                      const unsigned short* __restrict__ Wt,
                                                      const unsigned short* __restrict__ W2b,
                                                      float* __restrict__ acc, float scale) {
    __shared__ __align__(16) float UPool[4][1408];   // 22528 B

    int tid = threadIdx.x;
    int wid = tid >> 6, lane = tid & 63;
    int q = lane >> 4, c = lane & 15;        // matmul decomposition
    int qq = lane >> 3, cc = lane & 7;       // gather decomposition
    int tile = blockIdx.x * 4 + wid;
    if (tile >= NT_ALL) return;
    int rowbase = tile << 4;
    float* fw = &UPool[wid][0];
    unsigned short* pw = (unsigned short*)&UPool[wid][1088];

    // ---- phase 1: gather, two 8-row halves ----
#pragma unroll 1
    for (int half = 0; half < 2; ++half) {
        int prow = perm[rowbase + half * 8 + qq];
        int2 rm = rmeta[prow];
        int s = rm.x, pcv = rm.y;            // padded count (multiple of 4)
        float dr = dinv[prow];

        float a0 = 0.f, a1 = 0.f, a2 = 0.f, a3 = 0.f;
        float a4 = 0.f, a5 = 0.f, a6 = 0.f, a7 = 0.f;
        const unsigned short* eb = ebf + (cc << 3);

        // prologue: group0 fully issued; group1 addresses staged
        int e0 = (int)(col[s]     & 0x3FFFFu);
        int e1 = (int)(col[s + 1] & 0x3FFFFu);
        int e2 = (int)(col[s + 2] & 0x3FFFFu);
        int e3 = (int)(col[s + 3] & 0x3FFFFu);
        float g0 = dinv[e0], g1 = dinv[e1], g2 = dinv[e2], g3 = dinv[e3];
        uint4 u0 = *(const uint4*)(eb + ((size_t)e0 << 6));
        uint4 u1 = *(const uint4*)(eb + ((size_t)e1 << 6));
        uint4 u2 = *(const uint4*)(eb + ((size_t)e2 << 6));
        uint4 u3 = *(const uint4*)(eb + ((size_t)e3 << 6));
        int f0 = (int)(col[s + 4] & 0x3FFFFu);
        int f1 = (int)(col[s + 5] & 0x3FFFFu);
        int f2 = (int)(col[s + 6] & 0x3FFFFu);
        int f3 = (int)(col[s + 7] & 0x3FFFFu);

        for (int it = 0; it < pcv; it += 4) {
            // issue group it+4 loads
            float h0 = dinv[f0], h1 = dinv[f1], h2 = dinv[f2], h3 = dinv[f3];
            uint4 v0 = *(const uint4*)(eb + ((size_t)f0 << 6));
            uint4 v1 = *(const uint4*)(eb + ((size_t)f1 << 6));
            uint4 v2 = *(const uint4*)(eb + ((size_t)f2 << 6));
            uint4 v3 = *(const uint4*)(eb + ((size_t)f3 << 6));
            // issue col for group it+8
            int x0 = (int)(col[s + it + 8]  & 0x3FFFFu);
            int x1 = (int)(col[s + it + 9]  & 0x3FFFFu);
            int x2 = (int)(col[s + it + 10] & 0x3FFFFu);
            int x3 = (int)(col[s + it + 11] & 0x3FFFFu);
            // consume group it (no predication: pads have g==0, zero rows)
            a0 = fmaf(g0, bflo(u0.x), a0); a1 = fmaf(g0, bfhi(u0.x), a1);
            a2 = fmaf(g0, bflo(u0.y), a2); a3 = fmaf(g0, bfhi(u0.y), a3);
            a4 = fmaf(g0, bflo(u0.z), a4); a5 = fmaf(g0, bfhi(u0.z), a5);
            a6 = fmaf(g0, bflo(u0.w), a6); a7 = fmaf(g0, bfhi(u0.w), a7);
            a0 = fmaf(g1, bflo(u1.x), a0); a1 = fmaf(g1, bfhi(u1.x), a1);
            a2 = fmaf(g1, bflo(u1.y), a2); a3 = fmaf(g1, bfhi(u1.y), a3);
            a4 = fmaf(g1, bflo(u1.z), a4); a5 = fmaf(g1, bfhi(u1.z), a5);
            a6 = fmaf(g1, bflo(u1.w), a6); a7 = fmaf(g1, bfhi(u1.w), a7);
            a0 = fmaf(g2, bflo(u2.x), a0); a1 = fmaf(g2, bfhi(u2.x), a1);
            a2 = fmaf(g2, bflo(u2.y), a2); a3 = fmaf(g2, bfhi(u2.y), a3);
            a4 = fmaf(g2, bflo(u2.z), a4); a5 = fmaf(g2, bfhi(u2.z), a5);
            a6 = fmaf(g2, bflo(u2.w), a6); a7 = fmaf(g2, bfhi(u2.w), a7);
            a0 = fmaf(g3, bflo(u3.x), a0); a1 = fmaf(g3, bfhi(u3.x), a1);
            a2 = fmaf(g3, bflo(u3.y), a2); a3 = fmaf(g3, bfhi(u3.y), a3);
            a4 = fmaf(g3, bflo(u3.z), a4); a5 = fmaf(g3, bfhi(u3.z), a5);
            a6 = fmaf(g3, bflo(u3.w), a6); a7 = fmaf(g3, bfhi(u3.w), a7);
            // rotate pipeline
            u0 = v0; u1 = v1; u2 = v2; u3 = v3;
            g0 = h0; g1 = h1; g2 = h2; g3 = h3;
            f0 = x0; f1 = x1; f2 = x2; f3 = x3;
        }
        int fb = (half * 8 + qq) * 68 + (cc << 3);
        fw[fb + 0] = a0 * dr; fw[fb + 1] = a1 * dr;
        fw[fb + 2] = a2 * dr; fw[fb + 3] = a3 * dr;
        fw[fb + 4] = a4 * dr; fw[fb + 5] = a5 * dr;
        fw[fb + 6] = a6 * dr; fw[fb + 7] = a7 * dr;
    }

    // ---- phase 2: matmul1 S = E @ W ----
    int arow = perm[rowbase + c];
    const unsigned short* erow = ebf + ((size_t)arow << 6);
    bf16x8 A0 = *(const bf16x8*)(erow + (q << 3));
    bf16x8 A1 = *(const bf16x8*)(erow + 32 + (q << 3));
    f32x4 S[8];
#pragma unroll
    for (int t = 0; t < 8; ++t) {
        bf16x8 B0 = *(const bf16x8*)&Wt[(16 * t + c) * EMB + (q << 3)];
        bf16x8 B1 = *(const bf16x8*)&Wt[(16 * t + c) * EMB + 32 + (q << 3)];
        f32x4 z = {0.f, 0.f, 0.f, 0.f};
        z = __builtin_amdgcn_mfma_f32_16x16x32_bf16(A0, B0, z, 0, 0, 0);
        S[t] = __builtin_amdgcn_mfma_f32_16x16x32_bf16(A1, B1, z, 0, 0, 0);
    }

    // ---- phase 3: softmax over 128 intents, per C-row (row = 4q + r) ----
#pragma unroll
    for (int r = 0; r < 4; ++r) {
        float m = S[0][r];
#pragma unroll
        for (int t = 1; t < 8; ++t) m = fmaxf(m, S[t][r]);
        m = fmaxf(m, __shfl_xor(m, 1)); m = fmaxf(m, __shfl_xor(m, 2));
        m = fmaxf(m, __shfl_xor(m, 4)); m = fmaxf(m, __shfl_xor(m, 8));
        float sum = 0.f;
#pragma unroll
        for (int t = 0; t < 8; ++t) { float ex = __expf(S[t][r] - m); S[t][r] = ex; sum += ex; }
        sum += __shfl_xor(sum, 1); sum += __shfl_xor(sum, 2);
        sum += __shfl_xor(sum, 4); sum += __shfl_xor(sum, 8);
        float inv = 1.0f / sum;
#pragma unroll
        for (int t = 0; t < 8; ++t) S[t][r] *= inv;
    }

    // ---- phase 4: matmul2 O = P @ W^T, hi/lo bf16 split ----
    f32x4 O0 = {0.f, 0.f, 0.f, 0.f}, O1 = O0, O2 = O0, O3 = O0;
#pragma unroll
    for (int s2 = 0; s2 < 4; ++s2) {
#pragma unroll
        for (int h2 = 0; h2 < 2; ++h2) {
            int t = 2 * s2 + h2;
#pragma unroll
            for (int r = 0; r < 4; ++r) {
                float p = S[t][r];
                unsigned short b = f2bf(p);
                pw[(4 * q + r) * 40 + (h2 << 4) + c] = b;
                S[t][r] = p - bflo((unsigned int)b);
            }
        }
        bf16x8 Pf = *(const bf16x8*)&pw[c * 40 + (q << 3)];
        {
            bf16x8 Bf0 = *(const bf16x8*)&W2b[(c) * NI + (s2 << 5) + (q << 3)];
            bf16x8 Bf1 = *(const bf16x8*)&W2b[(16 + c) * NI + (s2 << 5) + (q << 3)];
            O0 = __builtin_amdgcn_mfma_f32_16x16x32_bf16(Pf, Bf0, O0, 0, 0, 0);
            O1 = __builtin_amdgcn_mfma_f32_16x16x32_bf16(Pf, Bf1, O1, 0, 0, 0);
            bf16x8 Bf2 = *(const bf16x8*)&W2b[(32 + c) * NI + (s2 << 5) + (q << 3)];
            bf16x8 Bf3 = *(const bf16x8*)&W2b[(48 + c) * NI + (s2 << 5) + (q << 3)];
            O2 = __builtin_amdgcn_mfma_f32_16x16x32_bf16(Pf, Bf2, O2, 0, 0, 0);
            O3 = __builtin_amdgcn_mfma_f32_16x16x32_bf16(Pf, Bf3, O3, 0, 0, 0);
        }
#pragma unroll
        for (int h2 = 0; h2 < 2; ++h2) {
            int t = 2 * s2 + h2;
#pragma unroll
            for (int r = 0; r < 4; ++r)
                pw[(4 * q + r) * 40 + (h2 << 4) + c] = f2bf(S[t][r]);
        }
        bf16x8 Pl = *(const bf16x8*)&pw[c * 40 + (q << 3)];
        {
            bf16x8 Bf0 = *(const bf16x8*)&W2b[(c) * NI + (s2 << 5) + (q << 3)];
            bf16x8 Bf1 = *(const bf16x8*)&W2b[(16 + c) * NI + (s2 << 5) + (q << 3)];
            O0 = __builtin_amdgcn_mfma_f32_16x16x32_bf16(Pl, Bf0, O0, 0, 0, 0);
            O1 = __builtin_amdgcn_mfma_f32_16x16x32_bf16(Pl, Bf1, O1, 0, 0, 0);
            bf16x8 Bf2 = *(const bf16x8*)&W2b[(32 + c) * NI + (s2 << 5) + (q << 3)];
            bf16x8 Bf3 = *(const bf16x8*)&W2b[(48 + c) * NI + (s2 << 5) + (q << 3)];
            O2 = __builtin_amdgcn_mfma_f32_16x16x32_bf16(Pl, Bf2, O2, 0, 0, 0);
            O3 = __builtin_amdgcn_mfma_f32_16x16x32_bf16(Pl, Bf3, O3, 0, 0, 0);
        }
    }

    asm volatile("" ::: "memory");

    // ---- phase 5a: fold O into fw (nv = gnn + O), wave-local ----
#pragma unroll
    for (int r = 0; r < 4; ++r) {
        int rl = 4 * q + r;
        float* gr = &fw[rl * 68];
        gr[c]      += O0[r];
        gr[16 + c] += O1[r];
        gr[32 + c] += O2[r];
        gr[48 + c] += O3[r];
    }

    // ---- phase 5b: coalesced write-out; lane = (row j, 16-float segment sg) ----
    {
        int j = lane >> 2, sg = lane & 3;
        int rw = perm[rowbase + j];
        const float* gr = &fw[j * 68 + (sg << 4)];
        float4 x0 = *(const float4*)&gr[0];
        float4 x1 = *(const float4*)&gr[4];
        float4 x2 = *(const float4*)&gr[8];
        float4 x3 = *(const float4*)&gr[12];
        size_t base = ((size_t)rw << 6) + (sg << 4);   // element index
        uint4 w0, w1;
        w0.x = (unsigned int)f2bf(x0.x) | ((unsigned int)f2bf(x0.y) << 16);
        w0.y = (unsigned int)f2bf(x0.z) | ((unsigned int)f2bf(x0.w) << 16);
        w0.z = (unsigned int)f2bf(x1.x) | ((unsigned int)f2bf(x1.y) << 16);
        w0.w = (unsigned int)f2bf(x1.z) | ((unsigned int)f2bf(x1.w) << 16);
        w1.x = (unsigned int)f2bf(x2.x) | ((unsigned int)f2bf(x2.y) << 16);
        w1.y = (unsigned int)f2bf(x2.z) | ((unsigned int)f2bf(x2.w) << 16);
        w1.z = (unsigned int)f2bf(x3.x) | ((unsigned int)f2bf(x3.y) << 16);
        w1.w = (unsigned int)f2bf(x3.z) | ((unsigned int)f2bf(x3.w) << 16);
        *(uint4*)(ebfout + base) = w0;
        *(uint4*)(ebfout + base + 8) = w1;
        if (rw < N_NODES) {
            float4* ap = (float4*)(acc + base);
            float4 b0 = ap[0], b1 = ap[1], b2 = ap[2], b3 = ap[3];
            b0.x = (b0.x + x0.x) * scale; b0.y = (b0.y + x0.y) * scale;
            b0.z = (b0.z + x0.z) * scale; b0.w = (b0.w + x0.w) * scale;
            b1.x = (b1.x + x1.x) * scale; b1.y = (b1.y + x1.y) * scale;
            b1.z = (b1.z + x1.z) * scale; b1.w = (b1.w + x1.w) * scale;
            b2.x = (b2.x + x2.x) * scale; b2.y = (b2.y + x2.y) * scale;
            b2.z = (b2.z + x2.z) * scale; b2.w = (b2.w + x2.w) * scale;
            b3.x = (b3.x + x3.x) * scale; b3.y = (b3.y + x3.y) * scale;
            b3.z = (b3.z + x3.z) * scale; b3.w = (b3.w + x3.w) * scale;
            ap[0] = b0; ap[1] = b1; ap[2] = b2; ap[3] = b3;
        }
    }
}

// ---- launch ----

extern "C" void kernel_launch(void* const* d_in, const int* in_sizes, int n_in,
                              void* d_out, int out_size, void* d_ws, size_t ws_size,
                              hipStream_t stream) {
    const float* ue = (const float*)d_in[0];
    const float* ie = (const float*)d_in[1];
    const float* W  = (const float*)d_in[2];
    const int*   h  = (const int*)d_in[3];
    const int*   t  = (const int*)d_in[4];
    float* out = (float*)d_out;

    // workspace (4-byte units), ~61 MB. Layout note: each ebf table is followed
    // by >=15 MB of workspace so masked stale prefetch indices (< 2^18) can
    // never read past the allocation.
    int*            gcur  = (int*)d_ws;                           // NB (pad to 2048)
    int2*           rmeta = (int2*)(gcur + 2048);                 // NPAD int2
    float*          dinv  = (float*)(rmeta + NPAD);               // NPAD
    int*            perm  = (int*)(dinv + NPAD);                  // NPAD
    unsigned short* ebfA  = (unsigned short*)(perm + NPAD);       // NPAD*64 ushort
    unsigned short* ebfB  = ebfA + (size_t)NPAD * EMB;            // NPAD*64 ushort
    unsigned int*   ebuf  = (unsigned int*)(ebfB + (size_t)NPAD * EMB); // NB*BSTRIDE + 16
    unsigned short* Wt    = (unsigned short*)(ebuf + NB * BSTRIDE + 16);
    unsigned short* W2b   = Wt + EMB * NI;

    hipMemsetAsync(gcur, 0, NB * sizeof(int), stream);
    hipMemsetAsync(ebuf + NB * BSTRIDE, 0, 16 * sizeof(unsigned int), stream);
    bucket_scatter<<<EGRID, 512, 0, stream>>>(h, t, gcur, ebuf);
    bucket_csr<<<NB, 512, 0, stream>>>(gcur, ebuf, rmeta, dinv, perm);
    init_kernel<<<(NPAD * EMB / 4 + 255) / 256, 256, 0, stream>>>(
        (const float4*)ue, (const float4*)ie, (uint2*)ebfA, (float4*)out);
    wconv<<<(EMB * NI + 255) / 256, 256, 0, stream>>>(W, Wt, W2b);

    const unsigned int* col = ebuf;
    spmm_intent<<<SBLK, 256, 0, stream>>>(rmeta, col, dinv, perm, ebfA, ebfB, Wt, W2b, out, 1.0f);
    spmm_intent<<<SBLK, 256, 0, stream>>>(rmeta, col, dinv, perm, ebfB, ebfA, Wt, W2b, out, 1.0f / 3.0f);
}

// Round 9
// 458.206 us; speedup vs baseline: 1.0650x; 1.0327x over previous
//
#include <hip/hip_runtime.h>
#include <math.h>

#define N_USERS 100000
#define N_ITEMS 50000
#define N_NODES 150000
#define EMB 64
#define NI 128
#define NUM_EDGES 4000000
#define NPAD 150016            // 1172 * 128
#define NB 1172                // buckets of 128 nodes
#define BSTRIDE 4352           // slots per bucket (mean 3413+pad<=384, sigma ~58)
#define ETILE 8192
#define EGRID ((NUM_EDGES + ETILE - 1) / ETILE)   // 489
#define NT_ALL (NPAD / 16)     // 9376 tiles (covers dummy pad nodes; writes guarded)
#define SBLK (NT_ALL / 4)      // 2344 blocks x 4 waves
#define SENT 150000u           // sentinel node: dinv==0, ebf row zeroed

typedef __attribute__((ext_vector_type(8))) short bf16x8;
typedef __attribute__((ext_vector_type(4))) float f32x4;

__device__ __forceinline__ unsigned short f2bf(float f) {
    unsigned int u = __float_as_uint(f);
    u += 0x7FFFu + ((u >> 16) & 1u);
    return (unsigned short)(u >> 16);
}
__device__ __forceinline__ float bflo(unsigned int u) { return __uint_as_float(u << 16); }
__device__ __forceinline__ float bfhi(unsigned int u) { return __uint_as_float(u & 0xFFFF0000u); }

// ---- bucket scatter: block-aggregated reservations into fixed-stride buckets ----

__global__ __launch_bounds__(512) void bucket_scatter(const int* __restrict__ h,
                                                      const int* __restrict__ t,
                                                      int* __restrict__ gcur,
                                                      unsigned int* __restrict__ ebuf) {
    __shared__ int lc[NB];
    __shared__ int lbase[NB];
    __shared__ int lcur[NB];
    int tid = threadIdx.x;
    for (int i = tid; i < NB; i += 512) lc[i] = 0;
    __syncthreads();
    int base = blockIdx.x * ETILE;
#pragma unroll
    for (int k = 0; k < ETILE / 512; ++k) {
        int idx = base + k * 512 + tid;
        if (idx < NUM_EDGES) atomicAdd(&lc[h[idx] >> 7], 1);
    }
    __syncthreads();
    for (int i = tid; i < NB; i += 512) {
        int c = lc[i];
        lbase[i] = c ? (i * BSTRIDE + atomicAdd(&gcur[i], c)) : 0;
        lcur[i] = 0;
    }
    __syncthreads();
#pragma unroll
    for (int k = 0; k < ETILE / 512; ++k) {
        int idx = base + k * 512 + tid;
        if (idx < NUM_EDGES) {
            int hh = h[idx], tt = t[idx];
            int b = hh >> 7;
            int p = lbase[b] + atomicAdd(&lcur[b], 1);
            int lim = b * BSTRIDE + BSTRIDE - 1;
            p = (p <= lim) ? p : lim;
            ebuf[p] = ((unsigned int)(hh & 127) << 18) | (unsigned int)tt;
        }
    }
}

// ---- per-bucket counting sort + pad-to-4 segments (no perm: R6/R8 showed
// reordering buys nothing; contiguity wins). Pad slots filled with SENT
// (dinv==0, ebf row zeroed) so the gather needs no predication/clamps. ----

__global__ __launch_bounds__(512) void bucket_csr(const int* __restrict__ gcur,
                                                  unsigned int* __restrict__ ebuf,
                                                  int2* __restrict__ rmeta,
                                                  float* __restrict__ dinv) {
    __shared__ unsigned int in_s[BSTRIDE];   // 17408 B
    __shared__ int cnt_s[128];
    __shared__ int base_s[128];
    __shared__ int sc[128];
    int b = blockIdx.x, tid = threadIdx.x;
    int s = b * BSTRIDE;
    int n = gcur[b];
    if (n > BSTRIDE) n = BSTRIDE;

    for (int i = tid; i < n; i += 512) in_s[i] = ebuf[s + i];
    if (tid < 128) cnt_s[tid] = 0;
    __syncthreads();
    for (int i = tid; i < n; i += 512) atomicAdd(&cnt_s[in_s[i] >> 18], 1);
    __syncthreads();

    int c = 0, pc = 0;
    if (tid < 128) {
        c = cnt_s[tid];
        pc = (c + 3) & ~3;              // pad each row segment to %4
        sc[tid] = pc;
    }
    __syncthreads();
    for (int off = 1; off < 128; off <<= 1) {
        int tv = 0;
        if (tid < 128 && tid >= off) tv = sc[tid - off];
        __syncthreads();
        if (tid < 128 && tid >= off) sc[tid] += tv;
        __syncthreads();
    }
    if (tid < 128) {
        int excl = sc[tid] - pc;
        base_s[tid] = excl;
        int node = (b << 7) + tid;
        rmeta[node] = make_int2(s + excl, pc);
        dinv[node] = (c > 0) ? rsqrtf((float)c) : 0.0f;
        for (int p2 = c; p2 < pc; ++p2) ebuf[s + excl + p2] = SENT;
        cnt_s[tid] = 0;
    }
    __syncthreads();
    for (int i = tid; i < n; i += 512) {
        unsigned int qv = in_s[i];
        int hl = (int)(qv >> 18);
        int p = base_s[hl] + atomicAdd(&cnt_s[hl], 1);
        ebuf[s + p] = qv & 0x3FFFFu;    // pure t index, sorted+padded position
    }
}

// ---- init: ebf = bf16(concat(user,item)) + zeroed dummy rows; acc = concat ----

__global__ void init_kernel(const float4* __restrict__ ue4, const float4* __restrict__ ie4,
                            uint2* __restrict__ ebf4, float4* __restrict__ out4) {
    int i = blockIdx.x * blockDim.x + threadIdx.x;
    const int uelems = N_USERS * EMB / 4;
    const int relems = N_NODES * EMB / 4;
    const int total  = NPAD * EMB / 4;
    if (i < total) {
        float4 v = make_float4(0.f, 0.f, 0.f, 0.f);
        if (i < uelems) v = ue4[i];
        else if (i < relems) v = ie4[i - uelems];
        if (i < relems) out4[i] = v;
        unsigned int p0 = ((unsigned int)f2bf(v.y) << 16) | f2bf(v.x);
        unsigned int p1 = ((unsigned int)f2bf(v.w) << 16) | f2bf(v.z);
        ebf4[i] = make_uint2(p0, p1);
    }
}

// ---- wconv: W fp32 -> two bf16 global tables (16 KB each, L1/L2-resident) ----

__global__ __launch_bounds__(256) void wconv(const float* __restrict__ W,
                                             unsigned short* __restrict__ Wt,
                                             unsigned short* __restrict__ W2b) {
    int i = blockIdx.x * 256 + threadIdx.x;
    if (i < EMB * NI) {
        int d = i >> 7, c = i & 127;
        unsigned short b = f2bf(W[i]);
        W2b[i] = b;                 // [dim][intent]
        Wt[c * EMB + d] = b;        // [intent][dim]
    }
}

// ---- fused SpMM + MFMA intent head (barrier-free) ----
// One 16-row tile per wave (contiguous rows). Block = 256 (4 waves).
// LDS 22528 B. __launch_bounds__(256,6): VGPR cap 85 so the forced 2-deep
// pipeline (u+v groups live simultaneously, ~70 VGPR) fits without spill.
//
// Gather: lane = (qq row 0..7, cc dim-oct 0..7); per-lane loop to its own
//   padded count. col via single aligned uint4/iter. sched_barrier(0) between
//   the load block and FMA block forces the compiler to KEEP the pipeline
//   (R8 post-mortem: VGPR=36 proved it was de-pipelining into serial loads).
//   Prefetch addresses clamped to last valid group (warm repeats, not
//   cold garbage lines).

__global__ __launch_bounds__(256, 6) void spmm_intent(const int2* __restrict__ rmeta,
                                                      const unsigned int* __restrict__ col,
                                                      const float* __restrict__ dinv,
                                                      const unsigned short* __restrict__ ebf,
                                                      unsigned short* __restrict__ ebfout,
                                                      const unsigned short* __restrict__ Wt,
                                                      const unsigned short* __restrict__ W2b,
                                                      float* __restrict__ acc, float scale) {
    __shared__ __align__(16) float UPool[4][1408];   // 22528 B

    int tid = threadIdx.x;
    int wid = tid >> 6, lane = tid & 63;
    int q = lane >> 4, c = lane & 15;        // matmul decomposition
    int qq = lane >> 3, cc = lane & 7;       // gather decomposition
    int tile = blockIdx.x * 4 + wid;
    if (tile >= NT_ALL) return;
    int rowbase = tile << 4;
    float* fw = &UPool[wid][0];
    unsigned short* pw = (unsigned short*)&UPool[wid][1088];

    // ---- phase 1: gather, two 8-row halves, enforced 2-deep pipeline ----
#pragma unroll 1
    for (int half = 0; half < 2; ++half) {
        int row = rowbase + half * 8 + qq;
        int2 rm = rmeta[row];
        int s = rm.x, pcv = rm.y;            // padded count (multiple of 4)
        float dr = dinv[row];

        float a0 = 0.f, a1 = 0.f, a2 = 0.f, a3 = 0.f;
        float a4 = 0.f, a5 = 0.f, a6 = 0.f, a7 = 0.f;
        const unsigned short* eb = ebf + (cc << 3);

        // prologue: group0 loads issued; group1 col staged (clamped)
        uint4 cg0 = *(const uint4*)&col[s];
        int e0 = (int)(cg0.x & 0x3FFFFu), e1 = (int)(cg0.y & 0x3FFFFu);
        int e2 = (int)(cg0.z & 0x3FFFFu), e3 = (int)(cg0.w & 0x3FFFFu);
        float g0 = dinv[e0], g1 = dinv[e1], g2 = dinv[e2], g3 = dinv[e3];
        uint4 u0 = *(const uint4*)(eb + ((size_t)e0 << 6));
        uint4 u1 = *(const uint4*)(eb + ((size_t)e1 << 6));
        uint4 u2 = *(const uint4*)(eb + ((size_t)e2 << 6));
        uint4 u3 = *(const uint4*)(eb + ((size_t)e3 << 6));
        uint4 cg1 = *(const uint4*)&col[s + ((pcv >= 8) ? 4 : 0)];
        int f0 = (int)(cg1.x & 0x3FFFFu), f1 = (int)(cg1.y & 0x3FFFFu);
        int f2 = (int)(cg1.z & 0x3FFFFu), f3 = (int)(cg1.w & 0x3FFFFu);

        for (int it = 0; it < pcv; it += 4) {
            // issue next group's loads (dinv + ebf) and the col for group+2
            float h0 = dinv[f0], h1 = dinv[f1], h2 = dinv[f2], h3 = dinv[f3];
            uint4 v0 = *(const uint4*)(eb + ((size_t)f0 << 6));
            uint4 v1 = *(const uint4*)(eb + ((size_t)f1 << 6));
            uint4 v2 = *(const uint4*)(eb + ((size_t)f2 << 6));
            uint4 v3 = *(const uint4*)(eb + ((size_t)f3 << 6));
            int cb = s + it + 8;
            int ce = s + pcv - 4;
            uint4 cgn = *(const uint4*)&col[(cb < ce) ? cb : ce];
            // fence: loads above may not sink below; FMAs may not hoist above
            __builtin_amdgcn_sched_barrier(0);
            // consume group it (loaded last iteration)
            a0 = fmaf(g0, bflo(u0.x), a0); a1 = fmaf(g0, bfhi(u0.x), a1);
            a2 = fmaf(g0, bflo(u0.y), a2); a3 = fmaf(g0, bfhi(u0.y), a3);
            a4 = fmaf(g0, bflo(u0.z), a4); a5 = fmaf(g0, bfhi(u0.z), a5);
            a6 = fmaf(g0, bflo(u0.w), a6); a7 = fmaf(g0, bfhi(u0.w), a7);
            a0 = fmaf(g1, bflo(u1.x), a0); a1 = fmaf(g1, bfhi(u1.x), a1);
            a2 = fmaf(g1, bflo(u1.y), a2); a3 = fmaf(g1, bfhi(u1.y), a3);
            a4 = fmaf(g1, bflo(u1.z), a4); a5 = fmaf(g1, bfhi(u1.z), a5);
            a6 = fmaf(g1, bflo(u1.w), a6); a7 = fmaf(g1, bfhi(u1.w), a7);
            a0 = fmaf(g2, bflo(u2.x), a0); a1 = fmaf(g2, bfhi(u2.x), a1);
            a2 = fmaf(g2, bflo(u2.y), a2); a3 = fmaf(g2, bfhi(u2.y), a3);
            a4 = fmaf(g2, bflo(u2.z), a4); a5 = fmaf(g2, bfhi(u2.z), a5);
            a6 = fmaf(g2, bflo(u2.w), a6); a7 = fmaf(g2, bfhi(u2.w), a7);
            a0 = fmaf(g3, bflo(u3.x), a0); a1 = fmaf(g3, bfhi(u3.x), a1);
            a2 = fmaf(g3, bflo(u3.y), a2); a3 = fmaf(g3, bfhi(u3.y), a3);
            a4 = fmaf(g3, bflo(u3.z), a4); a5 = fmaf(g3, bfhi(u3.z), a5);
            a6 = fmaf(g3, bflo(u3.w), a6); a7 = fmaf(g3, bfhi(u3.w), a7);
            // rotate pipeline
            u0 = v0; u1 = v1; u2 = v2; u3 = v3;
            g0 = h0; g1 = h1; g2 = h2; g3 = h3;
            f0 = (int)(cgn.x & 0x3FFFFu); f1 = (int)(cgn.y & 0x3FFFFu);
            f2 = (int)(cgn.z & 0x3FFFFu); f3 = (int)(cgn.w & 0x3FFFFu);
        }
        int fb = (half * 8 + qq) * 68 + (cc << 3);
        fw[fb + 0] = a0 * dr; fw[fb + 1] = a1 * dr;
        fw[fb + 2] = a2 * dr; fw[fb + 3] = a3 * dr;
        fw[fb + 4] = a4 * dr; fw[fb + 5] = a5 * dr;
        fw[fb + 6] = a6 * dr; fw[fb + 7] = a7 * dr;
    }

    // ---- phase 2: matmul1 S = E @ W (A rows contiguous: 2 KB block) ----
    const unsigned short* erow = ebf + ((size_t)(rowbase + c) << 6);
    bf16x8 A0 = *(const bf16x8*)(erow + (q << 3));
    bf16x8 A1 = *(const bf16x8*)(erow + 32 + (q << 3));
    f32x4 S[8];
#pragma unroll
    for (int t = 0; t < 8; ++t) {
        bf16x8 B0 = *(const bf16x8*)&Wt[(16 * t + c) * EMB + (q << 3)];
        bf16x8 B1 = *(const bf16x8*)&Wt[(16 * t + c) * EMB + 32 + (q << 3)];
        f32x4 z = {0.f, 0.f, 0.f, 0.f};
        z = __builtin_amdgcn_mfma_f32_16x16x32_bf16(A0, B0, z, 0, 0, 0);
        S[t] = __builtin_amdgcn_mfma_f32_16x16x32_bf16(A1, B1, z, 0, 0, 0);
    }

    // ---- phase 3: softmax over 128 intents, per C-row (row = 4q + r) ----
#pragma unroll
    for (int r = 0; r < 4; ++r) {
        float m = S[0][r];
#pragma unroll
        for (int t = 1; t < 8; ++t) m = fmaxf(m, S[t][r]);
        m = fmaxf(m, __shfl_xor(m, 1)); m = fmaxf(m, __shfl_xor(m, 2));
        m = fmaxf(m, __shfl_xor(m, 4)); m = fmaxf(m, __shfl_xor(m, 8));
        float sum = 0.f;
#pragma unroll
        for (int t = 0; t < 8; ++t) { float ex = __expf(S[t][r] - m); S[t][r] = ex; sum += ex; }
        sum += __shfl_xor(sum, 1); sum += __shfl_xor(sum, 2);
        sum += __shfl_xor(sum, 4); sum += __shfl_xor(sum, 8);
        float inv = 1.0f / sum;
#pragma unroll
        for (int t = 0; t < 8; ++t) S[t][r] *= inv;
    }

    // ---- phase 4: matmul2 O = P @ W^T, hi/lo bf16 split ----
    f32x4 O0 = {0.f, 0.f, 0.f, 0.f}, O1 = O0, O2 = O0, O3 = O0;
#pragma unroll
    for (int s2 = 0; s2 < 4; ++s2) {
#pragma unroll
        for (int h2 = 0; h2 < 2; ++h2) {
            int t = 2 * s2 + h2;
#pragma unroll
            for (int r = 0; r < 4; ++r) {
                float p = S[t][r];
                unsigned short b = f2bf(p);
                pw[(4 * q + r) * 40 + (h2 << 4) + c] = b;
                S[t][r] = p - bflo((unsigned int)b);
            }
        }
        bf16x8 Pf = *(const bf16x8*)&pw[c * 40 + (q << 3)];
        {
            bf16x8 Bf0 = *(const bf16x8*)&W2b[(c) * NI + (s2 << 5) + (q << 3)];
            bf16x8 Bf1 = *(const bf16x8*)&W2b[(16 + c) * NI + (s2 << 5) + (q << 3)];
            O0 = __builtin_amdgcn_mfma_f32_16x16x32_bf16(Pf, Bf0, O0, 0, 0, 0);
            O1 = __builtin_amdgcn_mfma_f32_16x16x32_bf16(Pf, Bf1, O1, 0, 0, 0);
            bf16x8 Bf2 = *(const bf16x8*)&W2b[(32 + c) * NI + (s2 << 5) + (q << 3)];
            bf16x8 Bf3 = *(const bf16x8*)&W2b[(48 + c) * NI + (s2 << 5) + (q << 3)];
            O2 = __builtin_amdgcn_mfma_f32_16x16x32_bf16(Pf, Bf2, O2, 0, 0, 0);
            O3 = __builtin_amdgcn_mfma_f32_16x16x32_bf16(Pf, Bf3, O3, 0, 0, 0);
        }
#pragma unroll
        for (int h2 = 0; h2 < 2; ++h2) {
            int t = 2 * s2 + h2;
#pragma unroll
            for (int r = 0; r < 4; ++r)
                pw[(4 * q + r) * 40 + (h2 << 4) + c] = f2bf(S[t][r]);
        }
        bf16x8 Pl = *(const bf16x8*)&pw[c * 40 + (q << 3)];
        {
            bf16x8 Bf0 = *(const bf16x8*)&W2b[(c) * NI + (s2 << 5) + (q << 3)];
            bf16x8 Bf1 = *(const bf16x8*)&W2b[(16 + c) * NI + (s2 << 5) + (q << 3)];
            O0 = __builtin_amdgcn_mfma_f32_16x16x32_bf16(Pl, Bf0, O0, 0, 0, 0);
            O1 = __builtin_amdgcn_mfma_f32_16x16x32_bf16(Pl, Bf1, O1, 0, 0, 0);
            bf16x8 Bf2 = *(const bf16x8*)&W2b[(32 + c) * NI + (s2 << 5) + (q << 3)];
            bf16x8 Bf3 = *(const bf16x8*)&W2b[(48 + c) * NI + (s2 << 5) + (q << 3)];
            O2 = __builtin_amdgcn_mfma_f32_16x16x32_bf16(Pl, Bf2, O2, 0, 0, 0);
            O3 = __builtin_amdgcn_mfma_f32_16x16x32_bf16(Pl, Bf3, O3, 0, 0, 0);
        }
    }

    asm volatile("" ::: "memory");

    // ---- phase 5a: fold O into fw (nv = gnn + O), wave-local ----
#pragma unroll
    for (int r = 0; r < 4; ++r) {
        int rl = 4 * q + r;
        float* gr = &fw[rl * 68];
        gr[c]      += O0[r];
        gr[16 + c] += O1[r];
        gr[32 + c] += O2[r];
        gr[48 + c] += O3[r];
    }

    // ---- phase 5b: coalesced write-out; lane = (row j, 16-float segment sg) ----
    {
        int j = lane >> 2, sg = lane & 3;
        int rw = rowbase + j;
        const float* gr = &fw[j * 68 + (sg << 4)];
        float4 x0 = *(const float4*)&gr[0];
        float4 x1 = *(const float4*)&gr[4];
        float4 x2 = *(const float4*)&gr[8];
        float4 x3 = *(const float4*)&gr[12];
        size_t base = ((size_t)rw << 6) + (sg << 4);   // element index
        uint4 w0, w1;
        w0.x = (unsigned int)f2bf(x0.x) | ((unsigned int)f2bf(x0.y) << 16);
        w0.y = (unsigned int)f2bf(x0.z) | ((unsigned int)f2bf(x0.w) << 16);
        w0.z = (unsigned int)f2bf(x1.x) | ((unsigned int)f2bf(x1.y) << 16);
        w0.w = (unsigned int)f2bf(x1.z) | ((unsigned int)f2bf(x1.w) << 16);
        w1.x = (unsigned int)f2bf(x2.x) | ((unsigned int)f2bf(x2.y) << 16);
        w1.y = (unsigned int)f2bf(x2.z) | ((unsigned int)f2bf(x2.w) << 16);
        w1.z = (unsigned int)f2bf(x3.x) | ((unsigned int)f2bf(x3.y) << 16);
        w1.w = (unsigned int)f2bf(x3.z) | ((unsigned int)f2bf(x3.w) << 16);
        *(uint4*)(ebfout + base) = w0;
        *(uint4*)(ebfout + base + 8) = w1;
        if (rw < N_NODES) {
            float4* ap = (float4*)(acc + base);
            float4 b0 = ap[0], b1 = ap[1], b2 = ap[2], b3 = ap[3];
            b0.x = (b0.x + x0.x) * scale; b0.y = (b0.y + x0.y) * scale;
            b0.z = (b0.z + x0.z) * scale; b0.w = (b0.w + x0.w) * scale;
            b1.x = (b1.x + x1.x) * scale; b1.y = (b1.y + x1.y) * scale;
            b1.z = (b1.z + x1.z) * scale; b1.w = (b1.w + x1.w) * scale;
            b2.x = (b2.x + x2.x) * scale; b2.y = (b2.y + x2.y) * scale;
            b2.z = (b2.z + x2.z) * scale; b2.w = (b2.w + x2.w) * scale;
            b3.x = (b3.x + x3.x) * scale; b3.y = (b3.y + x3.y) * scale;
            b3.z = (b3.z + x3.z) * scale; b3.w = (b3.w + x3.w) * scale;
            ap[0] = b0; ap[1] = b1; ap[2] = b2; ap[3] = b3;
        }
    }
}

// ---- launch ----

extern "C" void kernel_launch(void* const* d_in, const int* in_sizes, int n_in,
                              void* d_out, int out_size, void* d_ws, size_t ws_size,
                              hipStream_t stream) {
    const float* ue = (const float*)d_in[0];
    const float* ie = (const float*)d_in[1];
    const float* W  = (const float*)d_in[2];
    const int*   h  = (const int*)d_in[3];
    const int*   t  = (const int*)d_in[4];
    float* out = (float*)d_out;

    // workspace (4-byte units), ~61 MB. Layout note: each ebf table is followed
    // by >=15 MB of workspace so masked garbage indices (< 2^18) always read
    // in-bounds (values never consumed).
    int*            gcur  = (int*)d_ws;                           // NB (pad to 2048)
    int2*           rmeta = (int2*)(gcur + 2048);                 // NPAD int2
    float*          dinv  = (float*)(rmeta + NPAD);               // NPAD
    unsigned short* ebfA  = (unsigned short*)(dinv + NPAD);       // NPAD*64 ushort
    unsigned short* ebfB  = ebfA + (size_t)NPAD * EMB;            // NPAD*64 ushort
    unsigned int*   ebuf  = (unsigned int*)(ebfB + (size_t)NPAD * EMB); // NB*BSTRIDE + 16
    unsigned short* Wt    = (unsigned short*)(ebuf + NB * BSTRIDE + 16);
    unsigned short* W2b   = Wt + EMB * NI;

    hipMemsetAsync(gcur, 0, NB * sizeof(int), stream);
    hipMemsetAsync(ebuf + NB * BSTRIDE, 0, 16 * sizeof(unsigned int), stream);
    bucket_scatter<<<EGRID, 512, 0, stream>>>(h, t, gcur, ebuf);
    bucket_csr<<<NB, 512, 0, stream>>>(gcur, ebuf, rmeta, dinv);
    init_kernel<<<(NPAD * EMB / 4 + 255) / 256, 256, 0, stream>>>(
        (const float4*)ue, (const float4*)ie, (uint2*)ebfA, (float4*)out);
    wconv<<<(EMB * NI + 255) / 256, 256, 0, stream>>>(W, Wt, W2b);

    const unsigned int* col = ebuf;
    spmm_intent<<<SBLK, 256, 0, stream>>>(rmeta, col, dinv, ebfA, ebfB, Wt, W2b, out, 1.0f);
    spmm_intent<<<SBLK, 256, 0, stream>>>(rmeta, col, dinv, ebfB, ebfA, Wt, W2b, out, 1.0f / 3.0f);
}

// Round 10
// 443.154 us; speedup vs baseline: 1.1011x; 1.0340x over previous
//
#include <hip/hip_runtime.h>
#include <math.h>

#define N_USERS 100000
#define N_ITEMS 50000
#define N_NODES 150000
#define EMB 64
#define NI 128
#define NUM_EDGES 4000000
#define NPAD 150016            // 1172 * 128
#define NB 1172                // buckets of 128 nodes
#define BSTRIDE 4352           // slots per bucket (mean 3413+pad<=384, sigma ~58)
#define ETILE 8192
#define EGRID ((NUM_EDGES + ETILE - 1) / ETILE)   // 489
#define NT_ALL (NPAD / 16)     // 9376 tiles (covers dummy pad nodes; writes guarded)
#define SBLK (NT_ALL / 4)      // 2344 blocks x 4 waves
#define SENT 150000u           // sentinel node: dinv==0, ebf row zeroed

typedef __attribute__((ext_vector_type(8))) short bf16x8;
typedef __attribute__((ext_vector_type(4))) float f32x4;

__device__ __forceinline__ unsigned short f2bf(float f) {
    unsigned int u = __float_as_uint(f);
    u += 0x7FFFu + ((u >> 16) & 1u);
    return (unsigned short)(u >> 16);
}
__device__ __forceinline__ float bflo(unsigned int u) { return __uint_as_float(u << 16); }
__device__ __forceinline__ float bfhi(unsigned int u) { return __uint_as_float(u & 0xFFFF0000u); }

// ---- bucket scatter: block-aggregated reservations into fixed-stride buckets ----

__global__ __launch_bounds__(512) void bucket_scatter(const int* __restrict__ h,
                                                      const int* __restrict__ t,
                                                      int* __restrict__ gcur,
                                                      unsigned int* __restrict__ ebuf) {
    __shared__ int lc[NB];
    __shared__ int lbase[NB];
    __shared__ int lcur[NB];
    int tid = threadIdx.x;
    for (int i = tid; i < NB; i += 512) lc[i] = 0;
    __syncthreads();
    int base = blockIdx.x * ETILE;
#pragma unroll
    for (int k = 0; k < ETILE / 512; ++k) {
        int idx = base + k * 512 + tid;
        if (idx < NUM_EDGES) atomicAdd(&lc[h[idx] >> 7], 1);
    }
    __syncthreads();
    for (int i = tid; i < NB; i += 512) {
        int c = lc[i];
        lbase[i] = c ? (i * BSTRIDE + atomicAdd(&gcur[i], c)) : 0;
        lcur[i] = 0;
    }
    __syncthreads();
#pragma unroll
    for (int k = 0; k < ETILE / 512; ++k) {
        int idx = base + k * 512 + tid;
        if (idx < NUM_EDGES) {
            int hh = h[idx], tt = t[idx];
            int b = hh >> 7;
            int p = lbase[b] + atomicAdd(&lcur[b], 1);
            int lim = b * BSTRIDE + BSTRIDE - 1;
            p = (p <= lim) ? p : lim;
            ebuf[p] = ((unsigned int)(hh & 127) << 18) | (unsigned int)tt;
        }
    }
}

// ---- per-bucket counting sort + pad-to-4 segments ----
// De-contended: 8 per-wave histograms + per-wave cursors (atomic traffic /8).
// rmeta[node] = (padded start, padded count); pads filled with SENT.

__global__ __launch_bounds__(512) void bucket_csr(const int* __restrict__ gcur,
                                                  unsigned int* __restrict__ ebuf,
                                                  int2* __restrict__ rmeta,
                                                  float* __restrict__ dinv) {
    __shared__ unsigned int in_s[BSTRIDE];   // 17408 B
    __shared__ int cnt8[8][128];             // 4096 B (histogram, then cursors)
    __shared__ int wb8[8][128];              // 4096 B (per-wave base offsets)
    __shared__ int base_s[128];
    __shared__ int sc[128];
    int b = blockIdx.x, tid = threadIdx.x, wid = tid >> 6;
    int s = b * BSTRIDE;
    int n = gcur[b];
    if (n > BSTRIDE) n = BSTRIDE;

    for (int i = tid; i < n; i += 512) in_s[i] = ebuf[s + i];
    for (int i = tid; i < 1024; i += 512) ((int*)cnt8)[i] = 0;
    __syncthreads();
    for (int i = tid; i < n; i += 512) atomicAdd(&cnt8[wid][in_s[i] >> 18], 1);
    __syncthreads();

    int c = 0, pc = 0;
    if (tid < 128) {
        int acc = 0;
#pragma unroll
        for (int w = 0; w < 8; ++w) { wb8[w][tid] = acc; acc += cnt8[w][tid]; }
        c = acc;
        pc = (c + 3) & ~3;              // pad each row segment to %4
        sc[tid] = pc;
    }
    __syncthreads();
    for (int off = 1; off < 128; off <<= 1) {
        int tv = 0;
        if (tid < 128 && tid >= off) tv = sc[tid - off];
        __syncthreads();
        if (tid < 128 && tid >= off) sc[tid] += tv;
        __syncthreads();
    }
    if (tid < 128) {
        int excl = sc[tid] - pc;
        base_s[tid] = excl;
        int node = (b << 7) + tid;
        rmeta[node] = make_int2(s + excl, pc);
        dinv[node] = (c > 0) ? rsqrtf((float)c) : 0.0f;
        for (int p2 = c; p2 < pc; ++p2) ebuf[s + excl + p2] = SENT;
    }
    __syncthreads();
    for (int i = tid; i < 1024; i += 512) ((int*)cnt8)[i] = 0;   // now cursors
    __syncthreads();
    for (int i = tid; i < n; i += 512) {
        unsigned int qv = in_s[i];
        int hl = (int)(qv >> 18);
        int p = base_s[hl] + wb8[wid][hl] + atomicAdd(&cnt8[wid][hl], 1);
        ebuf[s + p] = qv & 0x3FFFFu;    // pure t index, sorted+padded position
    }
}

// ---- init: ebf = bf16(concat(user,item)) + zeroed dummy rows; acc = concat ----

__global__ void init_kernel(const float4* __restrict__ ue4, const float4* __restrict__ ie4,
                            uint2* __restrict__ ebf4, float4* __restrict__ out4) {
    int i = blockIdx.x * blockDim.x + threadIdx.x;
    const int uelems = N_USERS * EMB / 4;
    const int relems = N_NODES * EMB / 4;
    const int total  = NPAD * EMB / 4;
    if (i < total) {
        float4 v = make_float4(0.f, 0.f, 0.f, 0.f);
        if (i < uelems) v = ue4[i];
        else if (i < relems) v = ie4[i - uelems];
        if (i < relems) out4[i] = v;
        unsigned int p0 = ((unsigned int)f2bf(v.y) << 16) | f2bf(v.x);
        unsigned int p1 = ((unsigned int)f2bf(v.w) << 16) | f2bf(v.z);
        ebf4[i] = make_uint2(p0, p1);
    }
}

// ---- wconv: W fp32 -> two bf16 global tables (16 KB each, L1/L2-resident) ----

__global__ __launch_bounds__(256) void wconv(const float* __restrict__ W,
                                             unsigned short* __restrict__ Wt,
                                             unsigned short* __restrict__ W2b) {
    int i = blockIdx.x * 256 + threadIdx.x;
    if (i < EMB * NI) {
        int d = i >> 7, c = i & 127;
        unsigned short b = f2bf(W[i]);
        W2b[i] = b;                 // [dim][intent]
        Wt[c * EMB + d] = b;        // [intent][dim]
    }
}

// ---- fused SpMM + MFMA intent head (barrier-free, two-pass gather) ----
// One 16-row tile per wave. Block = 256 (4 waves). LDS 39936 B -> 4 blocks/CU.
//
// R9 lesson: the compiler de-pipelines any register-rotated software pipeline
// (VGPR stayed 40 across 3 attempts); the serial col->dinv->ebf chain costs
// ~2500 cyc/trip. Fix: REMOVE the chain from the loop.
//  Pass 1 (per 8-row half): bulk-load col segments (coalesced uint4, <=64
//    edges/row) and dinv[t] (8 independent scattered loads/lane, one wait)
//    into per-wave LDS buffers, stride 68 (conflict-free across rows).
//    Indices clamped to NPAD-1 (stale bucket-tail words are unconsumed but
//    must stay in-bounds).
//  Pass 2: trip = {LDS col/g reads -> 8 INDEPENDENT ebf loads -> 128 FMAs}.
//    No cross-load dependence in the loop; 8 loads issue before one wait.
//  Rows with pcv>64 (P ~ 6e-5 for this graph) take a direct-read remainder.

__global__ __launch_bounds__(256, 4) void spmm_intent(const int2* __restrict__ rmeta,
                                                      const unsigned int* __restrict__ col,
                                                      const float* __restrict__ dinv,
                                                      const unsigned short* __restrict__ ebf,
                                                      unsigned short* __restrict__ ebfout,
                                                      const unsigned short* __restrict__ Wt,
                                                      const unsigned short* __restrict__ W2b,
                                                      float* __restrict__ acc, float scale) {
    // per-wave: fw[0,1088) | pw[1088,1408) | colbuf[1408,1952) | gbuf[1952,2496)
    __shared__ __align__(16) float UPool[4][2496];   // 39936 B

    int tid = threadIdx.x;
    int wid = tid >> 6, lane = tid & 63;
    int q = lane >> 4, c = lane & 15;        // matmul decomposition
    int qq = lane >> 3, cc = lane & 7;       // gather decomposition
    int tile = blockIdx.x * 4 + wid;
    if (tile >= NT_ALL) return;
    int rowbase = tile << 4;
    float* fw = &UPool[wid][0];
    unsigned short* pw = (unsigned short*)&UPool[wid][1088];
    unsigned int* cb = (unsigned int*)&UPool[wid][1408];
    float* gb = &UPool[wid][1952];

    // ---- phase 1: gather, two 8-row halves ----
#pragma unroll 1
    for (int half = 0; half < 2; ++half) {
        int row = rowbase + half * 8 + qq;
        int2 rm = rmeta[row];
        int s = rm.x, pcv = rm.y;            // padded count (multiple of 4)
        float dr = dinv[row];

        // pass 1: lane cc fills entries [8cc, 8cc+8) of row qq
        {
            int eoff = cc << 3;
            uint4 c0 = *(const uint4*)&col[s + eoff];
            uint4 c1 = *(const uint4*)&col[s + eoff + 4];
            // clamp (stale bucket-tail words may exceed the node table)
            c0.x = (c0.x < NPAD) ? c0.x : (NPAD - 1);
            c0.y = (c0.y < NPAD) ? c0.y : (NPAD - 1);
            c0.z = (c0.z < NPAD) ? c0.z : (NPAD - 1);
            c0.w = (c0.w < NPAD) ? c0.w : (NPAD - 1);
            c1.x = (c1.x < NPAD) ? c1.x : (NPAD - 1);
            c1.y = (c1.y < NPAD) ? c1.y : (NPAD - 1);
            c1.z = (c1.z < NPAD) ? c1.z : (NPAD - 1);
            c1.w = (c1.w < NPAD) ? c1.w : (NPAD - 1);
            int lb = qq * 68 + eoff;
            *(uint4*)&cb[lb]     = c0;
            *(uint4*)&cb[lb + 4] = c1;
            float g0 = dinv[c0.x], g1 = dinv[c0.y], g2 = dinv[c0.z], g3 = dinv[c0.w];
            float g4 = dinv[c1.x], g5 = dinv[c1.y], g6 = dinv[c1.z], g7 = dinv[c1.w];
            gb[lb + 0] = (eoff + 0 < pcv) ? g0 : 0.f;
            gb[lb + 1] = (eoff + 1 < pcv) ? g1 : 0.f;
            gb[lb + 2] = (eoff + 2 < pcv) ? g2 : 0.f;
            gb[lb + 3] = (eoff + 3 < pcv) ? g3 : 0.f;
            gb[lb + 4] = (eoff + 4 < pcv) ? g4 : 0.f;
            gb[lb + 5] = (eoff + 5 < pcv) ? g5 : 0.f;
            gb[lb + 6] = (eoff + 6 < pcv) ? g6 : 0.f;
            gb[lb + 7] = (eoff + 7 < pcv) ? g7 : 0.f;
        }

        float a0 = 0.f, a1 = 0.f, a2 = 0.f, a3 = 0.f;
        float a4 = 0.f, a5 = 0.f, a6 = 0.f, a7 = 0.f;
        const unsigned short* eb = ebf + (cc << 3);
        const unsigned int* cbr = &cb[qq * 68];
        const float* gbr = &gb[qq * 68];
        int lim = (pcv < 64) ? pcv : 64;

        // pass 2: 8 edges per trip, all loads independent
        for (int it = 0; it < lim; it += 8) {
            uint4 ca = *(const uint4*)&cbr[it];
            uint4 cd = *(const uint4*)&cbr[it + 4];
            float4 ga = *(const float4*)&gbr[it];
            float4 gd = *(const float4*)&gbr[it + 4];
            uint4 u0 = *(const uint4*)(eb + ((size_t)ca.x << 6));
            uint4 u1 = *(const uint4*)(eb + ((size_t)ca.y << 6));
            uint4 u2 = *(const uint4*)(eb + ((size_t)ca.z << 6));
            uint4 u3 = *(const uint4*)(eb + ((size_t)ca.w << 6));
            uint4 u4 = *(const uint4*)(eb + ((size_t)cd.x << 6));
            uint4 u5 = *(const uint4*)(eb + ((size_t)cd.y << 6));
            uint4 u6 = *(const uint4*)(eb + ((size_t)cd.z << 6));
            uint4 u7 = *(const uint4*)(eb + ((size_t)cd.w << 6));
            a0 = fmaf(ga.x, bflo(u0.x), a0); a1 = fmaf(ga.x, bfhi(u0.x), a1);
            a2 = fmaf(ga.x, bflo(u0.y), a2); a3 = fmaf(ga.x, bfhi(u0.y), a3);
            a4 = fmaf(ga.x, bflo(u0.z), a4); a5 = fmaf(ga.x, bfhi(u0.z), a5);
            a6 = fmaf(ga.x, bflo(u0.w), a6); a7 = fmaf(ga.x, bfhi(u0.w), a7);
            a0 = fmaf(ga.y, bflo(u1.x), a0); a1 = fmaf(ga.y, bfhi(u1.x), a1);
            a2 = fmaf(ga.y, bflo(u1.y), a2); a3 = fmaf(ga.y, bfhi(u1.y), a3);
            a4 = fmaf(ga.y, bflo(u1.z), a4); a5 = fmaf(ga.y, bfhi(u1.z), a5);
            a6 = fmaf(ga.y, bflo(u1.w), a6); a7 = fmaf(ga.y, bfhi(u1.w), a7);
            a0 = fmaf(ga.z, bflo(u2.x), a0); a1 = fmaf(ga.z, bfhi(u2.x), a1);
            a2 = fmaf(ga.z, bflo(u2.y), a2); a3 = fmaf(ga.z, bfhi(u2.y), a3);
            a4 = fmaf(ga.z, bflo(u2.z), a4); a5 = fmaf(ga.z, bfhi(u2.z), a5);
            a6 = fmaf(ga.z, bflo(u2.w), a6); a7 = fmaf(ga.z, bfhi(u2.w), a7);
            a0 = fmaf(ga.w, bflo(u3.x), a0); a1 = fmaf(ga.w, bfhi(u3.x), a1);
            a2 = fmaf(ga.w, bflo(u3.y), a2); a3 = fmaf(ga.w, bfhi(u3.y), a3);
            a4 = fmaf(ga.w, bflo(u3.z), a4); a5 = fmaf(ga.w, bfhi(u3.z), a5);
            a6 = fmaf(ga.w, bflo(u3.w), a6); a7 = fmaf(ga.w, bfhi(u3.w), a7);
            a0 = fmaf(gd.x, bflo(u4.x), a0); a1 = fmaf(gd.x, bfhi(u4.x), a1);
            a2 = fmaf(gd.x, bflo(u4.y), a2); a3 = fmaf(gd.x, bfhi(u4.y), a3);
            a4 = fmaf(gd.x, bflo(u4.z), a4); a5 = fmaf(gd.x, bfhi(u4.z), a5);
            a6 = fmaf(gd.x, bflo(u4.w), a6); a7 = fmaf(gd.x, bfhi(u4.w), a7);
            a0 = fmaf(gd.y, bflo(u5.x), a0); a1 = fmaf(gd.y, bfhi(u5.x), a1);
            a2 = fmaf(gd.y, bflo(u5.y), a2); a3 = fmaf(gd.y, bfhi(u5.y), a3);
            a4 = fmaf(gd.y, bflo(u5.z), a4); a5 = fmaf(gd.y, bfhi(u5.z), a5);
            a6 = fmaf(gd.y, bflo(u5.w), a6); a7 = fmaf(gd.y, bfhi(u5.w), a7);
            a0 = fmaf(gd.z, bflo(u6.x), a0); a1 = fmaf(gd.z, bfhi(u6.x), a1);
            a2 = fmaf(gd.z, bflo(u6.y), a2); a3 = fmaf(gd.z, bfhi(u6.y), a3);
            a4 = fmaf(gd.z, bflo(u6.z), a4); a5 = fmaf(gd.z, bfhi(u6.z), a5);
            a6 = fmaf(gd.z, bflo(u6.w), a6); a7 = fmaf(gd.z, bfhi(u6.w), a7);
            a0 = fmaf(gd.w, bflo(u7.x), a0); a1 = fmaf(gd.w, bfhi(u7.x), a1);
            a2 = fmaf(gd.w, bflo(u7.y), a2); a3 = fmaf(gd.w, bfhi(u7.y), a3);
            a4 = fmaf(gd.w, bflo(u7.z), a4); a5 = fmaf(gd.w, bfhi(u7.z), a5);
            a6 = fmaf(gd.w, bflo(u7.w), a6); a7 = fmaf(gd.w, bfhi(u7.w), a7);
        }
        // remainder (pcv > 64): direct reads, effectively never taken
        for (int it = 64; it < pcv; it += 4) {
            uint4 cq = *(const uint4*)&col[s + it];
            float g0 = dinv[cq.x], g1 = dinv[cq.y], g2 = dinv[cq.z], g3 = dinv[cq.w];
            uint4 u0 = *(const uint4*)(eb + ((size_t)cq.x << 6));
            uint4 u1 = *(const uint4*)(eb + ((size_t)cq.y << 6));
            uint4 u2 = *(const uint4*)(eb + ((size_t)cq.z << 6));
            uint4 u3 = *(const uint4*)(eb + ((size_t)cq.w << 6));
            a0 = fmaf(g0, bflo(u0.x), a0); a1 = fmaf(g0, bfhi(u0.x), a1);
            a2 = fmaf(g0, bflo(u0.y), a2); a3 = fmaf(g0, bfhi(u0.y), a3);
            a4 = fmaf(g0, bflo(u0.z), a4); a5 = fmaf(g0, bfhi(u0.z), a5);
            a6 = fmaf(g0, bflo(u0.w), a6); a7 = fmaf(g0, bfhi(u0.w), a7);
            a0 = fmaf(g1, bflo(u1.x), a0); a1 = fmaf(g1, bfhi(u1.x), a1);
            a2 = fmaf(g1, bflo(u1.y), a2); a3 = fmaf(g1, bfhi(u1.y), a3);
            a4 = fmaf(g1, bflo(u1.z), a4); a5 = fmaf(g1, bfhi(u1.z), a5);
            a6 = fmaf(g1, bflo(u1.w), a6); a7 = fmaf(g1, bfhi(u1.w), a7);
            a0 = fmaf(g2, bflo(u2.x), a0); a1 = fmaf(g2, bfhi(u2.x), a1);
            a2 = fmaf(g2, bflo(u2.y), a2); a3 = fmaf(g2, bfhi(u2.y), a3);
            a4 = fmaf(g2, bflo(u2.z), a4); a5 = fmaf(g2, bfhi(u2.z), a5);
            a6 = fmaf(g2, bflo(u2.w), a6); a7 = fmaf(g2, bfhi(u2.w), a7);
            a0 = fmaf(g3, bflo(u3.x), a0); a1 = fmaf(g3, bfhi(u3.x), a1);
            a2 = fmaf(g3, bflo(u3.y), a2); a3 = fmaf(g3, bfhi(u3.y), a3);
            a4 = fmaf(g3, bflo(u3.z), a4); a5 = fmaf(g3, bfhi(u3.z), a5);
            a6 = fmaf(g3, bflo(u3.w), a6); a7 = fmaf(g3, bfhi(u3.w), a7);
        }
        int fb = (half * 8 + qq) * 68 + (cc << 3);
        fw[fb + 0] = a0 * dr; fw[fb + 1] = a1 * dr;
        fw[fb + 2] = a2 * dr; fw[fb + 3] = a3 * dr;
        fw[fb + 4] = a4 * dr; fw[fb + 5] = a5 * dr;
        fw[fb + 6] = a6 * dr; fw[fb + 7] = a7 * dr;
    }

    // ---- phase 2: matmul1 S = E @ W (A rows contiguous: 2 KB block) ----
    const unsigned short* erow = ebf + ((size_t)(rowbase + c) << 6);
    bf16x8 A0 = *(const bf16x8*)(erow + (q << 3));
    bf16x8 A1 = *(const bf16x8*)(erow + 32 + (q << 3));
    f32x4 S[8];
#pragma unroll
    for (int t = 0; t < 8; ++t) {
        bf16x8 B0 = *(const bf16x8*)&Wt[(16 * t + c) * EMB + (q << 3)];
        bf16x8 B1 = *(const bf16x8*)&Wt[(16 * t + c) * EMB + 32 + (q << 3)];
        f32x4 z = {0.f, 0.f, 0.f, 0.f};
        z = __builtin_amdgcn_mfma_f32_16x16x32_bf16(A0, B0, z, 0, 0, 0);
        S[t] = __builtin_amdgcn_mfma_f32_16x16x32_bf16(A1, B1, z, 0, 0, 0);
    }

    // ---- phase 3: softmax over 128 intents, per C-row (row = 4q + r) ----
#pragma unroll
    for (int r = 0; r < 4; ++r) {
        float m = S[0][r];
#pragma unroll
        for (int t = 1; t < 8; ++t) m = fmaxf(m, S[t][r]);
        m = fmaxf(m, __shfl_xor(m, 1)); m = fmaxf(m, __shfl_xor(m, 2));
        m = fmaxf(m, __shfl_xor(m, 4)); m = fmaxf(m, __shfl_xor(m, 8));
        float sum = 0.f;
#pragma unroll
        for (int t = 0; t < 8; ++t) { float ex = __expf(S[t][r] - m); S[t][r] = ex; sum += ex; }
        sum += __shfl_xor(sum, 1); sum += __shfl_xor(sum, 2);
        sum += __shfl_xor(sum, 4); sum += __shfl_xor(sum, 8);
        float inv = 1.0f / sum;
#pragma unroll
        for (int t = 0; t < 8; ++t) S[t][r] *= inv;
    }

    // ---- phase 4: matmul2 O = P @ W^T, hi/lo bf16 split ----
    f32x4 O0 = {0.f, 0.f, 0.f, 0.f}, O1 = O0, O2 = O0, O3 = O0;
#pragma unroll
    for (int s2 = 0; s2 < 4; ++s2) {
#pragma unroll
        for (int h2 = 0; h2 < 2; ++h2) {
            int t = 2 * s2 + h2;
#pragma unroll
            for (int r = 0; r < 4; ++r) {
                float p = S[t][r];
                unsigned short b = f2bf(p);
                pw[(4 * q + r) * 40 + (h2 << 4) + c] = b;
                S[t][r] = p - bflo((unsigned int)b);
            }
        }
        bf16x8 Pf = *(const bf16x8*)&pw[c * 40 + (q << 3)];
        {
            bf16x8 Bf0 = *(const bf16x8*)&W2b[(c) * NI + (s2 << 5) + (q << 3)];
            bf16x8 Bf1 = *(const bf16x8*)&W2b[(16 + c) * NI + (s2 << 5) + (q << 3)];
            O0 = __builtin_amdgcn_mfma_f32_16x16x32_bf16(Pf, Bf0, O0, 0, 0, 0);
            O1 = __builtin_amdgcn_mfma_f32_16x16x32_bf16(Pf, Bf1, O1, 0, 0, 0);
            bf16x8 Bf2 = *(const bf16x8*)&W2b[(32 + c) * NI + (s2 << 5) + (q << 3)];
            bf16x8 Bf3 = *(const bf16x8*)&W2b[(48 + c) * NI + (s2 << 5) + (q << 3)];
            O2 = __builtin_amdgcn_mfma_f32_16x16x32_bf16(Pf, Bf2, O2, 0, 0, 0);
            O3 = __builtin_amdgcn_mfma_f32_16x16x32_bf16(Pf, Bf3, O3, 0, 0, 0);
        }
#pragma unroll
        for (int h2 = 0; h2 < 2; ++h2) {
            int t = 2 * s2 + h2;
#pragma unroll
            for (int r = 0; r < 4; ++r)
                pw[(4 * q + r) * 40 + (h2 << 4) + c] = f2bf(S[t][r]);
        }
        bf16x8 Pl = *(const bf16x8*)&pw[c * 40 + (q << 3)];
        {
            bf16x8 Bf0 = *(const bf16x8*)&W2b[(c) * NI + (s2 << 5) + (q << 3)];
            bf16x8 Bf1 = *(const bf16x8*)&W2b[(16 + c) * NI + (s2 << 5) + (q << 3)];
            O0 = __builtin_amdgcn_mfma_f32_16x16x32_bf16(Pl, Bf0, O0, 0, 0, 0);
            O1 = __builtin_amdgcn_mfma_f32_16x16x32_bf16(Pl, Bf1, O1, 0, 0, 0);
            bf16x8 Bf2 = *(const bf16x8*)&W2b[(32 + c) * NI + (s2 << 5) + (q << 3)];
            bf16x8 Bf3 = *(const bf16x8*)&W2b[(48 + c) * NI + (s2 << 5) + (q << 3)];
            O2 = __builtin_amdgcn_mfma_f32_16x16x32_bf16(Pl, Bf2, O2, 0, 0, 0);
            O3 = __builtin_amdgcn_mfma_f32_16x16x32_bf16(Pl, Bf3, O3, 0, 0, 0);
        }
    }

    asm volatile("" ::: "memory");

    // ---- phase 5a: fold O into fw (nv = gnn + O), wave-local ----
#pragma unroll
    for (int r = 0; r < 4; ++r) {
        int rl = 4 * q + r;
        float* gr = &fw[rl * 68];
        gr[c]      += O0[r];
        gr[16 + c] += O1[r];
        gr[32 + c] += O2[r];
        gr[48 + c] += O3[r];
    }

    // ---- phase 5b: coalesced write-out; lane = (row j, 16-float segment sg) ----
    {
        int j = lane >> 2, sg = lane & 3;
        int rw = rowbase + j;
        const float* gr = &fw[j * 68 + (sg << 4)];
        float4 x0 = *(const float4*)&gr[0];
        float4 x1 = *(const float4*)&gr[4];
        float4 x2 = *(const float4*)&gr[8];
        float4 x3 = *(const float4*)&gr[12];
        size_t base = ((size_t)rw << 6) + (sg << 4);   // element index
        uint4 w0, w1;
        w0.x = (unsigned int)f2bf(x0.x) | ((unsigned int)f2bf(x0.y) << 16);
        w0.y = (unsigned int)f2bf(x0.z) | ((unsigned int)f2bf(x0.w) << 16);
        w0.z = (unsigned int)f2bf(x1.x) | ((unsigned int)f2bf(x1.y) << 16);
        w0.w = (unsigned int)f2bf(x1.z) | ((unsigned int)f2bf(x1.w) << 16);
        w1.x = (unsigned int)f2bf(x2.x) | ((unsigned int)f2bf(x2.y) << 16);
        w1.y = (unsigned int)f2bf(x2.z) | ((unsigned int)f2bf(x2.w) << 16);
        w1.z = (unsigned int)f2bf(x3.x) | ((unsigned int)f2bf(x3.y) << 16);
        w1.w = (unsigned int)f2bf(x3.z) | ((unsigned int)f2bf(x3.w) << 16);
        *(uint4*)(ebfout + base) = w0;
        *(uint4*)(ebfout + base + 8) = w1;
        if (rw < N_NODES) {
            float4* ap = (float4*)(acc + base);
            float4 b0 = ap[0], b1 = ap[1], b2 = ap[2], b3 = ap[3];
            b0.x = (b0.x + x0.x) * scale; b0.y = (b0.y + x0.y) * scale;
            b0.z = (b0.z + x0.z) * scale; b0.w = (b0.w + x0.w) * scale;
            b1.x = (b1.x + x1.x) * scale; b1.y = (b1.y + x1.y) * scale;
            b1.z = (b1.z + x1.z) * scale; b1.w = (b1.w + x1.w) * scale;
            b2.x = (b2.x + x2.x) * scale; b2.y = (b2.y + x2.y) * scale;
            b2.z = (b2.z + x2.z) * scale; b2.w = (b2.w + x2.w) * scale;
            b3.x = (b3.x + x3.x) * scale; b3.y = (b3.y + x3.y) * scale;
            b3.z = (b3.z + x3.z) * scale; b3.w = (b3.w + x3.w) * scale;
            ap[0] = b0; ap[1] = b1; ap[2] = b2; ap[3] = b3;
        }
    }
}

// ---- launch ----

extern "C" void kernel_launch(void* const* d_in, const int* in_sizes, int n_in,
                              void* d_out, int out_size, void* d_ws, size_t ws_size,
                              hipStream_t stream) {
    const float* ue = (const float*)d_in[0];
    const float* ie = (const float*)d_in[1];
    const float* W  = (const float*)d_in[2];
    const int*   h  = (const int*)d_in[3];
    const int*   t  = (const int*)d_in[4];
    float* out = (float*)d_out;

    // workspace (4-byte units), ~61 MB. All gather indices are clamped to
    // NPAD-1, so every ebf/dinv access stays within its table.
    int*            gcur  = (int*)d_ws;                           // NB (pad to 2048)
    int2*           rmeta = (int2*)(gcur + 2048);                 // NPAD int2
    float*          dinv  = (float*)(rmeta + NPAD);               // NPAD
    unsigned short* ebfA  = (unsigned short*)(dinv + NPAD);       // NPAD*64 ushort
    unsigned short* ebfB  = ebfA + (size_t)NPAD * EMB;            // NPAD*64 ushort
    unsigned int*   ebuf  = (unsigned int*)(ebfB + (size_t)NPAD * EMB); // NB*BSTRIDE + 16
    unsigned short* Wt    = (unsigned short*)(ebuf + NB * BSTRIDE + 16);
    unsigned short* W2b   = Wt + EMB * NI;

    hipMemsetAsync(gcur, 0, NB * sizeof(int), stream);
    hipMemsetAsync(ebuf + NB * BSTRIDE, 0, 16 * sizeof(unsigned int), stream);
    bucket_scatter<<<EGRID, 512, 0, stream>>>(h, t, gcur, ebuf);
    bucket_csr<<<NB, 512, 0, stream>>>(gcur, ebuf, rmeta, dinv);
    init_kernel<<<(NPAD * EMB / 4 + 255) / 256, 256, 0, stream>>>(
        (const float4*)ue, (const float4*)ie, (uint2*)ebfA, (float4*)out);
    wconv<<<(EMB * NI + 255) / 256, 256, 0, stream>>>(W, Wt, W2b);

    const unsigned int* col = ebuf;
    spmm_intent<<<SBLK, 256, 0, stream>>>(rmeta, col, dinv, ebfA, ebfB, Wt, W2b, out, 1.0f);
    spmm_intent<<<SBLK, 256, 0, stream>>>(rmeta, col, dinv, ebfB, ebfA, Wt, W2b, out, 1.0f / 3.0f);
}